// Round 4
// baseline (738.045 us; speedup 1.0000x reference)
//
#include <hip/hip_runtime.h>
#include <math.h>
#include <stdint.h>

#define N_NODES 100000
#define N_EDGES 1600000
#define N_GRAPHS 64

// ---------------- workspace layout (bytes) ----------------
// cnt     @ 0        : 100000 int
// fill    @ 400128   : 100000 int
// row_ptr @ 800256   : 100001 int
// col     @ 1200384  : 1600000 int (6.4 MB)
// pooled  @ 7600384  : 64*64 float
// bsum    @ 7616768  : 128 int
// M       @ 7617408  : 100000*64 float (25.6 MB)   mean / h (in-place)
// A       @ 33217408 : 100000*64 float (25.6 MB)
// total ~58.8 MB

__device__ __forceinline__ void atomicMaxFloat(float* addr, float val) {
    if (val >= 0.0f) {
        atomicMax((int*)addr, __float_as_int(val));
    } else {
        atomicMin((unsigned int*)addr, __float_as_uint(val));
    }
}

__global__ void k_init(int* __restrict__ cnt, int* __restrict__ fill,
                       float* __restrict__ pooled) {
    int i = blockIdx.x * blockDim.x + threadIdx.x;
    if (i < N_NODES) { cnt[i] = 0; fill[i] = 0; }
    if (i < N_GRAPHS * 64) pooled[i] = -INFINITY;
}

__global__ void k_hist(const int* __restrict__ dst, int* __restrict__ cnt) {
    int e = blockIdx.x * blockDim.x + threadIdx.x;
    if (e < N_EDGES) atomicAdd(&cnt[dst[e]], 1);
}

#define SCAN_CHUNK 1024

__global__ void k_scan1(const int* __restrict__ cnt, int* __restrict__ bsum) {
    __shared__ int lds[256];
    int b = blockIdx.x, t = threadIdx.x;
    int base = b * SCAN_CHUNK + t * 4;
    int s = 0;
#pragma unroll
    for (int j = 0; j < 4; ++j) {
        int i = base + j;
        if (i < N_NODES) s += cnt[i];
    }
    lds[t] = s;
    __syncthreads();
    for (int off = 128; off > 0; off >>= 1) {
        if (t < off) lds[t] += lds[t + off];
        __syncthreads();
    }
    if (t == 0) bsum[b] = lds[0];
}

__global__ void k_scan2(int* __restrict__ bsum, int nb) {
    if (threadIdx.x == 0 && blockIdx.x == 0) {
        int acc = 0;
        for (int i = 0; i < nb; ++i) { int v = bsum[i]; bsum[i] = acc; acc += v; }
    }
}

__global__ void k_scan3(const int* __restrict__ cnt, const int* __restrict__ bsum,
                        int* __restrict__ row_ptr) {
    __shared__ int lds[256];
    int b = blockIdx.x, t = threadIdx.x;
    int base = b * SCAN_CHUNK + t * 4;
    int v[4];
    int s = 0;
#pragma unroll
    for (int j = 0; j < 4; ++j) {
        int i = base + j;
        v[j] = (i < N_NODES) ? cnt[i] : 0;
        s += v[j];
    }
    lds[t] = s;
    __syncthreads();
    for (int off = 1; off < 256; off <<= 1) {
        int add = (t >= off) ? lds[t - off] : 0;
        __syncthreads();
        lds[t] += add;
        __syncthreads();
    }
    int ex = bsum[b] + ((t > 0) ? lds[t - 1] : 0);
#pragma unroll
    for (int j = 0; j < 4; ++j) {
        int i = base + j;
        if (i < N_NODES) { ex += v[j]; row_ptr[i + 1] = ex; }
    }
    if (b == 0 && t == 0) row_ptr[0] = 0;
}

__global__ void k_fill(const int* __restrict__ src, const int* __restrict__ dst,
                       const int* __restrict__ row_ptr, int* __restrict__ fill,
                       int* __restrict__ col) {
    int e = blockIdx.x * blockDim.x + threadIdx.x;
    if (e < N_EDGES) {
        int d = dst[e];
        int pos = atomicAdd(&fill[d], 1);
        col[row_ptr[d] + pos] = src[e];
    }
}

// ---------------------------------------------------------------------------
// Aggregation only: mean[node][0..FIN) (stride 64) = mean over neighbors of h
// One wave owns NC contiguous nodes; row_ptr for all of them loaded in ONE
// lane-parallel load. No LDS, low VGPR -> high occupancy, deep gather MLP.
// ---------------------------------------------------------------------------
#define NC 16

template <int FIN>
__global__ __launch_bounds__(256) void k_agg(
    const float* __restrict__ h, const int* __restrict__ row_ptr,
    const int* __restrict__ col, float* __restrict__ mean) {
    int lane = threadIdx.x & 63;
    int wave = blockIdx.x * 4 + (threadIdx.x >> 6);
    int base = wave * NC;
    if (base >= N_NODES) return;
    // lanes 0..NC hold row_ptr[base+lane]
    int rp = row_ptr[base + (lane < NC ? lane : NC)];

    for (int i = 0; i < NC; ++i) {
        int node = base + i;
        int start = __shfl(rp, i);
        int end   = __shfl(rp, i + 1);
        float s = 0.0f;

        if constexpr (FIN == 64) {
            for (int eb = start; eb < end; eb += 64) {
                int n = end - eb; if (n > 64) n = 64;
                int c = (eb + lane < end) ? col[eb + lane] : 0;
                int j = 0;
                for (; j + 7 < n; j += 8) {
                    int c0 = __shfl(c, j),     c1 = __shfl(c, j + 1);
                    int c2 = __shfl(c, j + 2), c3 = __shfl(c, j + 3);
                    int c4 = __shfl(c, j + 4), c5 = __shfl(c, j + 5);
                    int c6 = __shfl(c, j + 6), c7 = __shfl(c, j + 7);
                    float a0 = h[c0 * 64 + lane], a1 = h[c1 * 64 + lane];
                    float a2 = h[c2 * 64 + lane], a3 = h[c3 * 64 + lane];
                    float a4 = h[c4 * 64 + lane], a5 = h[c5 * 64 + lane];
                    float a6 = h[c6 * 64 + lane], a7 = h[c7 * 64 + lane];
                    s += ((a0 + a1) + (a2 + a3)) + ((a4 + a5) + (a6 + a7));
                }
                for (; j + 3 < n; j += 4) {
                    int c0 = __shfl(c, j),     c1 = __shfl(c, j + 1);
                    int c2 = __shfl(c, j + 2), c3 = __shfl(c, j + 3);
                    float a0 = h[c0 * 64 + lane], a1 = h[c1 * 64 + lane];
                    float a2 = h[c2 * 64 + lane], a3 = h[c3 * 64 + lane];
                    s += (a0 + a1) + (a2 + a3);
                }
                for (; j < n; ++j) {
                    int cc = __shfl(c, j);
                    s += h[cc * 64 + lane];
                }
            }
        } else {  // FIN == 32: halves of the wave take alternating edges
            int k = lane & 31;
            int half = lane >> 5;
            for (int eb = start; eb < end; eb += 64) {
                int n = end - eb; if (n > 64) n = 64;
                int c = (eb + lane < end) ? col[eb + lane] : 0;
                int j = 0;
                for (; j + 7 < n; j += 8) {
                    int c0 = __shfl(c, j + half);
                    int c1 = __shfl(c, j + 2 + half);
                    int c2 = __shfl(c, j + 4 + half);
                    int c3 = __shfl(c, j + 6 + half);
                    float a0 = h[c0 * 32 + k], a1 = h[c1 * 32 + k];
                    float a2 = h[c2 * 32 + k], a3 = h[c3 * 32 + k];
                    s += (a0 + a1) + (a2 + a3);
                }
                for (; j < n; j += 2) {
                    if (j + half < n) {
                        int cc = __shfl(c, j + half);
                        s += h[cc * 32 + k];
                    }
                }
            }
            s += __shfl_xor(s, 32);
        }

        int deg = end - start;
        float m = (deg > 0) ? s / (float)deg : 0.0f;
        if (FIN == 64 || lane < 32) mean[node * 64 + (FIN == 64 ? lane : (lane & 31))] = m;
    }
}

// ---------------------------------------------------------------------------
// Dense transform: out[node][f] = sum_k mean[node][k]*Wl[k][f]
//                              +  sum_k x[node][k]*Wr[k][f]  + bl[f]
// lane = output feature. Weight COLUMNS pinned in VGPRs: __launch_bounds__
// (256,1) lifts the register cap to 512 so the compiler does NOT re-fetch
// them per node (R3 bug: VGPR_Count=84 => weights reloaded from global every
// node -> VMEM-issue bound). Two nodes per iteration give ILP to hide the
// wave-uniform row-load latency. No LDS, no shuffles in the hot loop.
// May run in-place (out == mean or x): a node's rows are fully consumed
// before its store, and each node is owned by exactly one wave.
// ---------------------------------------------------------------------------
template <int FIN, int XS>
__global__ __launch_bounds__(256, 1) void k_dense(
    const float* mean,            // stride 64, first FIN valid (may alias out)
    const float* x,               // stride XS (may alias out)
    const float* __restrict__ Wl, const float* __restrict__ bl,
    const float* __restrict__ Wr, float* out) {
    int lane = threadIdx.x & 63;
    float wl[FIN], wr[FIN];
#pragma unroll
    for (int k = 0; k < FIN; ++k) wl[k] = Wl[k * 64 + lane];  // coalesced
#pragma unroll
    for (int k = 0; k < FIN; ++k) wr[k] = Wr[k * 64 + lane];
    float blf = bl[lane];

    int wave = blockIdx.x * 4 + (threadIdx.x >> 6);
    int nWaves = gridDim.x * 4;

    int node = wave * 2;
    int stride = nWaves * 2;
    for (; node + 1 < N_NODES; node += stride) {
        const float4* mrow0 = (const float4*)(mean + (size_t)node * 64);
        const float4* xrow0 = (const float4*)(x + (size_t)node * XS);
        const float4* mrow1 = (const float4*)(mean + (size_t)(node + 1) * 64);
        const float4* xrow1 = (const float4*)(x + (size_t)(node + 1) * XS);
        float a0 = blf, a1 = 0.0f, a2 = 0.0f, a3 = 0.0f;
        float b0 = blf, b1 = 0.0f, b2 = 0.0f, b3 = 0.0f;
#pragma unroll
        for (int q = 0; q < FIN / 4; ++q) {
            float4 m0 = mrow0[q];
            float4 m1 = mrow1[q];
            a0 += m0.x * wl[4 * q + 0];
            a1 += m0.y * wl[4 * q + 1];
            a2 += m0.z * wl[4 * q + 2];
            a3 += m0.w * wl[4 * q + 3];
            b0 += m1.x * wl[4 * q + 0];
            b1 += m1.y * wl[4 * q + 1];
            b2 += m1.z * wl[4 * q + 2];
            b3 += m1.w * wl[4 * q + 3];
        }
#pragma unroll
        for (int q = 0; q < XS / 4; ++q) {
            float4 x0 = xrow0[q];
            float4 x1 = xrow1[q];
            a0 += x0.x * wr[4 * q + 0];
            a1 += x0.y * wr[4 * q + 1];
            a2 += x0.z * wr[4 * q + 2];
            a3 += x0.w * wr[4 * q + 3];
            b0 += x1.x * wr[4 * q + 0];
            b1 += x1.y * wr[4 * q + 1];
            b2 += x1.z * wr[4 * q + 2];
            b3 += x1.w * wr[4 * q + 3];
        }
        out[(size_t)node * 64 + lane] = (a0 + a1) + (a2 + a3);
        out[(size_t)(node + 1) * 64 + lane] = (b0 + b1) + (b2 + b3);
    }
    if (node < N_NODES) {  // tail (N_NODES even: unreachable, kept for safety)
        const float4* mrow0 = (const float4*)(mean + (size_t)node * 64);
        const float4* xrow0 = (const float4*)(x + (size_t)node * XS);
        float a0 = blf, a1 = 0.0f, a2 = 0.0f, a3 = 0.0f;
#pragma unroll
        for (int q = 0; q < FIN / 4; ++q) {
            float4 m0 = mrow0[q];
            a0 += m0.x * wl[4 * q + 0];
            a1 += m0.y * wl[4 * q + 1];
            a2 += m0.z * wl[4 * q + 2];
            a3 += m0.w * wl[4 * q + 3];
        }
#pragma unroll
        for (int q = 0; q < XS / 4; ++q) {
            float4 x0 = xrow0[q];
            a0 += x0.x * wr[4 * q + 0];
            a1 += x0.y * wr[4 * q + 1];
            a2 += x0.z * wr[4 * q + 2];
            a3 += x0.w * wr[4 * q + 3];
        }
        out[(size_t)node * 64 + lane] = (a0 + a1) + (a2 + a3);
    }
}

__global__ __launch_bounds__(256) void k_pool(const float* __restrict__ h,
                                              const int* __restrict__ batch,
                                              float* __restrict__ pooled) {
    int lane = threadIdx.x & 63;
    int wave = (blockIdx.x * blockDim.x + threadIdx.x) >> 6;
    int nWaves = (gridDim.x * blockDim.x) >> 6;
    int per = (N_NODES + nWaves - 1) / nWaves;
    int beg = wave * per;
    int end = beg + per; if (end > N_NODES) end = N_NODES;
    if (beg >= end) return;
    int curg = batch[beg];
    float m = -INFINITY;
    for (int i = beg; i < end; ++i) {
        int g = batch[i];
        if (g != curg) {
            atomicMaxFloat(&pooled[curg * 64 + lane], m);
            m = -INFINITY;
            curg = g;
        }
        m = fmaxf(m, h[(size_t)i * 64 + lane]);
    }
    atomicMaxFloat(&pooled[curg * 64 + lane], m);
}

__global__ void k_head(const float* __restrict__ pooled,
                       const float* __restrict__ Wout,
                       const float* __restrict__ bout, float* __restrict__ out) {
    int tid = threadIdx.x;          // 512 threads: g = tid>>3, o = tid&7
    int g = tid >> 3, o = tid & 7;
    float acc = bout[o];
#pragma unroll
    for (int k = 0; k < 64; ++k) acc += pooled[g * 64 + k] * Wout[k * 8 + o];
    float mx = acc;
#pragma unroll
    for (int m = 1; m < 8; m <<= 1) mx = fmaxf(mx, __shfl_xor(mx, m));
    float ex = expf(acc - mx);
    float sum = ex;
#pragma unroll
    for (int m = 1; m < 8; m <<= 1) sum += __shfl_xor(sum, m);
    out[g * 8 + o] = (acc - mx) - logf(sum);
}

extern "C" void kernel_launch(void* const* d_in, const int* in_sizes, int n_in,
                              void* d_out, int out_size, void* d_ws, size_t ws_size,
                              hipStream_t stream) {
    const float* x    = (const float*)d_in[0];
    const float* Wl0  = (const float*)d_in[1];
    const float* bl0  = (const float*)d_in[2];
    const float* Wr0  = (const float*)d_in[3];
    const float* Wl1  = (const float*)d_in[4];
    const float* bl1  = (const float*)d_in[5];
    const float* Wr1  = (const float*)d_in[6];
    const float* Wl2  = (const float*)d_in[7];
    const float* bl2  = (const float*)d_in[8];
    const float* Wr2  = (const float*)d_in[9];
    const float* Wout = (const float*)d_in[10];
    const float* bout = (const float*)d_in[11];
    const int*   eidx = (const int*)d_in[12];
    const int*   batch= (const int*)d_in[13];
    const int* src = eidx;
    const int* dst = eidx + N_EDGES;

    uint8_t* ws = (uint8_t*)d_ws;
    int*   cnt     = (int*)(ws + 0);
    int*   fill    = (int*)(ws + 400128);
    int*   row_ptr = (int*)(ws + 800256);
    int*   col     = (int*)(ws + 1200384);
    float* pooled  = (float*)(ws + 7600384);
    int*   bsum    = (int*)(ws + 7616768);
    float* M       = (float*)(ws + 7617408);
    float* A       = (float*)(ws + 33217408);

    int nb = (N_NODES + SCAN_CHUNK - 1) / SCAN_CHUNK;  // 98

    k_init<<<(N_NODES + 255) / 256, 256, 0, stream>>>(cnt, fill, pooled);
    k_hist<<<(N_EDGES + 255) / 256, 256, 0, stream>>>(dst, cnt);
    k_scan1<<<nb, 256, 0, stream>>>(cnt, bsum);
    k_scan2<<<1, 64, 0, stream>>>(bsum, nb);
    k_scan3<<<nb, 256, 0, stream>>>(cnt, bsum, row_ptr);
    k_fill<<<(N_EDGES + 255) / 256, 256, 0, stream>>>(src, dst, row_ptr, fill, col);

    int aggBlocks = (N_NODES / NC + 3) / 4;  // 1563

    // layer 0: mean0 -> M (stride 64), h1 = dense in-place -> M
    k_agg<32><<<aggBlocks, 256, 0, stream>>>(x, row_ptr, col, M);
    k_dense<32, 32><<<2048, 256, 0, stream>>>(M, x, Wl0, bl0, Wr0, M);
    // layer 1: mean1 -> A, h2 in-place -> A
    k_agg<64><<<aggBlocks, 256, 0, stream>>>(M, row_ptr, col, A);
    k_dense<64, 64><<<2048, 256, 0, stream>>>(A, M, Wl1, bl1, Wr1, A);
    // layer 2: mean2 -> M, h3 in-place -> M
    k_agg<64><<<aggBlocks, 256, 0, stream>>>(A, row_ptr, col, M);
    k_dense<64, 64><<<2048, 256, 0, stream>>>(M, A, Wl2, bl2, Wr2, M);

    k_pool<<<256, 256, 0, stream>>>(M, batch, pooled);
    k_head<<<1, 512, 0, stream>>>(pooled, Wout, bout, (float*)d_out);
}

// Round 5
// 734.401 us; speedup vs baseline: 1.0050x; 1.0050x over previous
//
#include <hip/hip_runtime.h>
#include <math.h>
#include <stdint.h>

#define N_NODES 100000
#define N_EDGES 1600000
#define N_GRAPHS 64

// ---------------- workspace layout (bytes) ----------------
// cnt     @ 0        : 100000 int
// fill    @ 400128   : 100000 int
// row_ptr @ 800256   : 100001 int
// col     @ 1200384  : 1600000 int (6.4 MB)
// pooled  @ 7600384  : 64*64 float
// bsum    @ 7616768  : 128 int
// M       @ 7617408  : 100000*64 float (25.6 MB)   mean / h (in-place)
// A       @ 33217408 : 100000*64 float (25.6 MB)
// total ~58.8 MB

__device__ __forceinline__ void atomicMaxFloat(float* addr, float val) {
    if (val >= 0.0f) {
        atomicMax((int*)addr, __float_as_int(val));
    } else {
        atomicMin((unsigned int*)addr, __float_as_uint(val));
    }
}

__global__ void k_init(int* __restrict__ cnt, int* __restrict__ fill,
                       float* __restrict__ pooled) {
    int i = blockIdx.x * blockDim.x + threadIdx.x;
    if (i < N_NODES) { cnt[i] = 0; fill[i] = 0; }
    if (i < N_GRAPHS * 64) pooled[i] = -INFINITY;
}

__global__ void k_hist(const int* __restrict__ dst, int* __restrict__ cnt) {
    int e = blockIdx.x * blockDim.x + threadIdx.x;
    if (e < N_EDGES) atomicAdd(&cnt[dst[e]], 1);
}

#define SCAN_CHUNK 1024

__global__ void k_scan1(const int* __restrict__ cnt, int* __restrict__ bsum) {
    __shared__ int lds[256];
    int b = blockIdx.x, t = threadIdx.x;
    int base = b * SCAN_CHUNK + t * 4;
    int s = 0;
#pragma unroll
    for (int j = 0; j < 4; ++j) {
        int i = base + j;
        if (i < N_NODES) s += cnt[i];
    }
    lds[t] = s;
    __syncthreads();
    for (int off = 128; off > 0; off >>= 1) {
        if (t < off) lds[t] += lds[t + off];
        __syncthreads();
    }
    if (t == 0) bsum[b] = lds[0];
}

__global__ void k_scan2(int* __restrict__ bsum, int nb) {
    if (threadIdx.x == 0 && blockIdx.x == 0) {
        int acc = 0;
        for (int i = 0; i < nb; ++i) { int v = bsum[i]; bsum[i] = acc; acc += v; }
    }
}

__global__ void k_scan3(const int* __restrict__ cnt, const int* __restrict__ bsum,
                        int* __restrict__ row_ptr) {
    __shared__ int lds[256];
    int b = blockIdx.x, t = threadIdx.x;
    int base = b * SCAN_CHUNK + t * 4;
    int v[4];
    int s = 0;
#pragma unroll
    for (int j = 0; j < 4; ++j) {
        int i = base + j;
        v[j] = (i < N_NODES) ? cnt[i] : 0;
        s += v[j];
    }
    lds[t] = s;
    __syncthreads();
    for (int off = 1; off < 256; off <<= 1) {
        int add = (t >= off) ? lds[t - off] : 0;
        __syncthreads();
        lds[t] += add;
        __syncthreads();
    }
    int ex = bsum[b] + ((t > 0) ? lds[t - 1] : 0);
#pragma unroll
    for (int j = 0; j < 4; ++j) {
        int i = base + j;
        if (i < N_NODES) { ex += v[j]; row_ptr[i + 1] = ex; }
    }
    if (b == 0 && t == 0) row_ptr[0] = 0;
}

__global__ void k_fill(const int* __restrict__ src, const int* __restrict__ dst,
                       const int* __restrict__ row_ptr, int* __restrict__ fill,
                       int* __restrict__ col) {
    int e = blockIdx.x * blockDim.x + threadIdx.x;
    if (e < N_EDGES) {
        int d = dst[e];
        int pos = atomicAdd(&fill[d], 1);
        col[row_ptr[d] + pos] = src[e];
    }
}

// ---------------------------------------------------------------------------
// Aggregation only: mean[node][0..FIN) (stride 64) = mean over neighbors of h
// One wave owns NC contiguous nodes; row_ptr for all of them loaded in ONE
// lane-parallel load. No LDS, low VGPR -> high occupancy, deep gather MLP.
// ---------------------------------------------------------------------------
#define NC 16

template <int FIN>
__global__ __launch_bounds__(256) void k_agg(
    const float* __restrict__ h, const int* __restrict__ row_ptr,
    const int* __restrict__ col, float* __restrict__ mean) {
    int lane = threadIdx.x & 63;
    int wave = blockIdx.x * 4 + (threadIdx.x >> 6);
    int base = wave * NC;
    if (base >= N_NODES) return;
    // lanes 0..NC hold row_ptr[base+lane]
    int rp = row_ptr[base + (lane < NC ? lane : NC)];

    for (int i = 0; i < NC; ++i) {
        int node = base + i;
        int start = __shfl(rp, i);
        int end   = __shfl(rp, i + 1);
        float s = 0.0f;

        if constexpr (FIN == 64) {
            for (int eb = start; eb < end; eb += 64) {
                int n = end - eb; if (n > 64) n = 64;
                int c = (eb + lane < end) ? col[eb + lane] : 0;
                int j = 0;
                for (; j + 7 < n; j += 8) {
                    int c0 = __shfl(c, j),     c1 = __shfl(c, j + 1);
                    int c2 = __shfl(c, j + 2), c3 = __shfl(c, j + 3);
                    int c4 = __shfl(c, j + 4), c5 = __shfl(c, j + 5);
                    int c6 = __shfl(c, j + 6), c7 = __shfl(c, j + 7);
                    float a0 = h[c0 * 64 + lane], a1 = h[c1 * 64 + lane];
                    float a2 = h[c2 * 64 + lane], a3 = h[c3 * 64 + lane];
                    float a4 = h[c4 * 64 + lane], a5 = h[c5 * 64 + lane];
                    float a6 = h[c6 * 64 + lane], a7 = h[c7 * 64 + lane];
                    s += ((a0 + a1) + (a2 + a3)) + ((a4 + a5) + (a6 + a7));
                }
                for (; j + 3 < n; j += 4) {
                    int c0 = __shfl(c, j),     c1 = __shfl(c, j + 1);
                    int c2 = __shfl(c, j + 2), c3 = __shfl(c, j + 3);
                    float a0 = h[c0 * 64 + lane], a1 = h[c1 * 64 + lane];
                    float a2 = h[c2 * 64 + lane], a3 = h[c3 * 64 + lane];
                    s += (a0 + a1) + (a2 + a3);
                }
                for (; j < n; ++j) {
                    int cc = __shfl(c, j);
                    s += h[cc * 64 + lane];
                }
            }
        } else {  // FIN == 32: halves of the wave take alternating edges
            int k = lane & 31;
            int half = lane >> 5;
            for (int eb = start; eb < end; eb += 64) {
                int n = end - eb; if (n > 64) n = 64;
                int c = (eb + lane < end) ? col[eb + lane] : 0;
                int j = 0;
                for (; j + 7 < n; j += 8) {
                    int c0 = __shfl(c, j + half);
                    int c1 = __shfl(c, j + 2 + half);
                    int c2 = __shfl(c, j + 4 + half);
                    int c3 = __shfl(c, j + 6 + half);
                    float a0 = h[c0 * 32 + k], a1 = h[c1 * 32 + k];
                    float a2 = h[c2 * 32 + k], a3 = h[c3 * 32 + k];
                    s += (a0 + a1) + (a2 + a3);
                }
                for (; j < n; j += 2) {
                    if (j + half < n) {
                        int cc = __shfl(c, j + half);
                        s += h[cc * 32 + k];
                    }
                }
            }
            s += __shfl_xor(s, 32);
        }

        int deg = end - start;
        float m = (deg > 0) ? s / (float)deg : 0.0f;
        if (FIN == 64 || lane < 32) mean[node * 64 + (FIN == 64 ? lane : (lane & 31))] = m;
    }
}

// ---------------------------------------------------------------------------
// Dense transform: out[node][f] = sum_k mean[node][k]*Wl[k][f]
//                              +  sum_k x[node][k]*Wr[k][f]  + bl[f]
// lane = output feature. Weight COLUMNS pinned in VGPRs. R4 bug: the compiler
// rematerialized the Wl/Wr loads inside the node loop (VGPR_Count=92) ->
// VMEM-issue bound on ~128 redundant weight loads/node-pair. Fix: empty
// inline-asm "+v" on every weight element after the preload — the compiler
// must treat the value as redefined and keep it live in a VGPR; it can no
// longer re-load from global. __launch_bounds__(256,1) gives it the register
// budget (128 weights + accs + addressing < 512).
// May run in-place (out == mean or x): a node's rows are fully consumed
// before its store, and each node is owned by exactly one wave.
// ---------------------------------------------------------------------------
template <int FIN, int XS>
__global__ __launch_bounds__(256, 1) void k_dense(
    const float* mean,            // stride 64, first FIN valid (may alias out)
    const float* x,               // stride XS (may alias out)
    const float* __restrict__ Wl, const float* __restrict__ bl,
    const float* __restrict__ Wr, float* out) {
    int lane = threadIdx.x & 63;
    float wl[FIN], wr[FIN];
#pragma unroll
    for (int k = 0; k < FIN; ++k) wl[k] = Wl[k * 64 + lane];  // coalesced
#pragma unroll
    for (int k = 0; k < FIN; ++k) wr[k] = Wr[k * 64 + lane];
    // Pin: forbid rematerialization of the weight loads inside the node loop.
#pragma unroll
    for (int k = 0; k < FIN; ++k) {
        asm volatile("" : "+v"(wl[k]));
        asm volatile("" : "+v"(wr[k]));
    }
    float blf = bl[lane];

    int wave = blockIdx.x * 4 + (threadIdx.x >> 6);
    int nWaves = gridDim.x * 4;

    int node = wave * 2;
    int stride = nWaves * 2;
    for (; node + 1 < N_NODES; node += stride) {
        const float4* mrow0 = (const float4*)(mean + (size_t)node * 64);
        const float4* xrow0 = (const float4*)(x + (size_t)node * XS);
        const float4* mrow1 = (const float4*)(mean + (size_t)(node + 1) * 64);
        const float4* xrow1 = (const float4*)(x + (size_t)(node + 1) * XS);
        float a0 = blf, a1 = 0.0f, a2 = 0.0f, a3 = 0.0f;
        float b0 = blf, b1 = 0.0f, b2 = 0.0f, b3 = 0.0f;
#pragma unroll
        for (int q = 0; q < FIN / 4; ++q) {
            float4 m0 = mrow0[q];
            float4 m1 = mrow1[q];
            a0 += m0.x * wl[4 * q + 0];
            a1 += m0.y * wl[4 * q + 1];
            a2 += m0.z * wl[4 * q + 2];
            a3 += m0.w * wl[4 * q + 3];
            b0 += m1.x * wl[4 * q + 0];
            b1 += m1.y * wl[4 * q + 1];
            b2 += m1.z * wl[4 * q + 2];
            b3 += m1.w * wl[4 * q + 3];
        }
#pragma unroll
        for (int q = 0; q < XS / 4; ++q) {
            float4 x0 = xrow0[q];
            float4 x1 = xrow1[q];
            a0 += x0.x * wr[4 * q + 0];
            a1 += x0.y * wr[4 * q + 1];
            a2 += x0.z * wr[4 * q + 2];
            a3 += x0.w * wr[4 * q + 3];
            b0 += x1.x * wr[4 * q + 0];
            b1 += x1.y * wr[4 * q + 1];
            b2 += x1.z * wr[4 * q + 2];
            b3 += x1.w * wr[4 * q + 3];
        }
        out[(size_t)node * 64 + lane] = (a0 + a1) + (a2 + a3);
        out[(size_t)(node + 1) * 64 + lane] = (b0 + b1) + (b2 + b3);
    }
    if (node < N_NODES) {  // tail (N_NODES even: unreachable, kept for safety)
        const float4* mrow0 = (const float4*)(mean + (size_t)node * 64);
        const float4* xrow0 = (const float4*)(x + (size_t)node * XS);
        float a0 = blf, a1 = 0.0f, a2 = 0.0f, a3 = 0.0f;
#pragma unroll
        for (int q = 0; q < FIN / 4; ++q) {
            float4 m0 = mrow0[q];
            a0 += m0.x * wl[4 * q + 0];
            a1 += m0.y * wl[4 * q + 1];
            a2 += m0.z * wl[4 * q + 2];
            a3 += m0.w * wl[4 * q + 3];
        }
#pragma unroll
        for (int q = 0; q < XS / 4; ++q) {
            float4 x0 = xrow0[q];
            a0 += x0.x * wr[4 * q + 0];
            a1 += x0.y * wr[4 * q + 1];
            a2 += x0.z * wr[4 * q + 2];
            a3 += x0.w * wr[4 * q + 3];
        }
        out[(size_t)node * 64 + lane] = (a0 + a1) + (a2 + a3);
    }
}

__global__ __launch_bounds__(256) void k_pool(const float* __restrict__ h,
                                              const int* __restrict__ batch,
                                              float* __restrict__ pooled) {
    int lane = threadIdx.x & 63;
    int wave = (blockIdx.x * blockDim.x + threadIdx.x) >> 6;
    int nWaves = (gridDim.x * blockDim.x) >> 6;
    int per = (N_NODES + nWaves - 1) / nWaves;
    int beg = wave * per;
    int end = beg + per; if (end > N_NODES) end = N_NODES;
    if (beg >= end) return;
    int curg = batch[beg];
    float m = -INFINITY;
    for (int i = beg; i < end; ++i) {
        int g = batch[i];
        if (g != curg) {
            atomicMaxFloat(&pooled[curg * 64 + lane], m);
            m = -INFINITY;
            curg = g;
        }
        m = fmaxf(m, h[(size_t)i * 64 + lane]);
    }
    atomicMaxFloat(&pooled[curg * 64 + lane], m);
}

__global__ void k_head(const float* __restrict__ pooled,
                       const float* __restrict__ Wout,
                       const float* __restrict__ bout, float* __restrict__ out) {
    int tid = threadIdx.x;          // 512 threads: g = tid>>3, o = tid&7
    int g = tid >> 3, o = tid & 7;
    float acc = bout[o];
#pragma unroll
    for (int k = 0; k < 64; ++k) acc += pooled[g * 64 + k] * Wout[k * 8 + o];
    float mx = acc;
#pragma unroll
    for (int m = 1; m < 8; m <<= 1) mx = fmaxf(mx, __shfl_xor(mx, m));
    float ex = expf(acc - mx);
    float sum = ex;
#pragma unroll
    for (int m = 1; m < 8; m <<= 1) sum += __shfl_xor(sum, m);
    out[g * 8 + o] = (acc - mx) - logf(sum);
}

extern "C" void kernel_launch(void* const* d_in, const int* in_sizes, int n_in,
                              void* d_out, int out_size, void* d_ws, size_t ws_size,
                              hipStream_t stream) {
    const float* x    = (const float*)d_in[0];
    const float* Wl0  = (const float*)d_in[1];
    const float* bl0  = (const float*)d_in[2];
    const float* Wr0  = (const float*)d_in[3];
    const float* Wl1  = (const float*)d_in[4];
    const float* bl1  = (const float*)d_in[5];
    const float* Wr1  = (const float*)d_in[6];
    const float* Wl2  = (const float*)d_in[7];
    const float* bl2  = (const float*)d_in[8];
    const float* Wr2  = (const float*)d_in[9];
    const float* Wout = (const float*)d_in[10];
    const float* bout = (const float*)d_in[11];
    const int*   eidx = (const int*)d_in[12];
    const int*   batch= (const int*)d_in[13];
    const int* src = eidx;
    const int* dst = eidx + N_EDGES;

    uint8_t* ws = (uint8_t*)d_ws;
    int*   cnt     = (int*)(ws + 0);
    int*   fill    = (int*)(ws + 400128);
    int*   row_ptr = (int*)(ws + 800256);
    int*   col     = (int*)(ws + 1200384);
    float* pooled  = (float*)(ws + 7600384);
    int*   bsum    = (int*)(ws + 7616768);
    float* M       = (float*)(ws + 7617408);
    float* A       = (float*)(ws + 33217408);

    int nb = (N_NODES + SCAN_CHUNK - 1) / SCAN_CHUNK;  // 98

    k_init<<<(N_NODES + 255) / 256, 256, 0, stream>>>(cnt, fill, pooled);
    k_hist<<<(N_EDGES + 255) / 256, 256, 0, stream>>>(dst, cnt);
    k_scan1<<<nb, 256, 0, stream>>>(cnt, bsum);
    k_scan2<<<1, 64, 0, stream>>>(bsum, nb);
    k_scan3<<<nb, 256, 0, stream>>>(cnt, bsum, row_ptr);
    k_fill<<<(N_EDGES + 255) / 256, 256, 0, stream>>>(src, dst, row_ptr, fill, col);

    int aggBlocks = (N_NODES / NC + 3) / 4;  // 1563

    // layer 0: mean0 -> M (stride 64), h1 = dense in-place -> M
    k_agg<32><<<aggBlocks, 256, 0, stream>>>(x, row_ptr, col, M);
    k_dense<32, 32><<<2048, 256, 0, stream>>>(M, x, Wl0, bl0, Wr0, M);
    // layer 1: mean1 -> A, h2 in-place -> A
    k_agg<64><<<aggBlocks, 256, 0, stream>>>(M, row_ptr, col, A);
    k_dense<64, 64><<<2048, 256, 0, stream>>>(A, M, Wl1, bl1, Wr1, A);
    // layer 2: mean2 -> M, h3 in-place -> M
    k_agg<64><<<aggBlocks, 256, 0, stream>>>(A, row_ptr, col, M);
    k_dense<64, 64><<<2048, 256, 0, stream>>>(M, A, Wl2, bl2, Wr2, M);

    k_pool<<<256, 256, 0, stream>>>(M, batch, pooled);
    k_head<<<1, 512, 0, stream>>>(pooled, Wout, bout, (float*)d_out);
}

// Round 6
// 671.309 us; speedup vs baseline: 1.0994x; 1.0940x over previous
//
#include <hip/hip_runtime.h>
#include <math.h>
#include <stdint.h>

#define N_NODES 100000
#define N_EDGES 1600000
#define N_GRAPHS 64

// ---------------- workspace layout (bytes) ----------------
// cnt     @ 0        : 100000 int
// fill    @ 400128   : 100000 int
// row_ptr @ 800256   : 100001 int
// col     @ 1200384  : 1600000 int (6.4 MB)
// pooled  @ 7600384  : 64*64 float
// bsum    @ 7616768  : 128 int
// M       @ 7617408  : 100000*64 float (25.6 MB)   mean / h (in-place)
// A       @ 33217408 : 100000*64 float (25.6 MB)
// total ~58.8 MB

__device__ __forceinline__ void atomicMaxFloat(float* addr, float val) {
    if (val >= 0.0f) {
        atomicMax((int*)addr, __float_as_int(val));
    } else {
        atomicMin((unsigned int*)addr, __float_as_uint(val));
    }
}

__device__ __forceinline__ float bcast_lane(float v, int k) {
    // wave-uniform broadcast of lane k -> SGPR; feeds v_fmac_f32 as the
    // scalar operand (1 SGPR read per VALU instr is legal).
    return __uint_as_float(__builtin_amdgcn_readlane(__float_as_uint(v), k));
}

__global__ void k_init(int* __restrict__ cnt, int* __restrict__ fill,
                       float* __restrict__ pooled) {
    int i = blockIdx.x * blockDim.x + threadIdx.x;
    if (i < N_NODES) { cnt[i] = 0; fill[i] = 0; }
    if (i < N_GRAPHS * 64) pooled[i] = -INFINITY;
}

__global__ void k_hist(const int* __restrict__ dst, int* __restrict__ cnt) {
    int e = blockIdx.x * blockDim.x + threadIdx.x;
    if (e < N_EDGES) atomicAdd(&cnt[dst[e]], 1);
}

#define SCAN_CHUNK 1024

__global__ void k_scan1(const int* __restrict__ cnt, int* __restrict__ bsum) {
    __shared__ int lds[256];
    int b = blockIdx.x, t = threadIdx.x;
    int base = b * SCAN_CHUNK + t * 4;
    int s = 0;
#pragma unroll
    for (int j = 0; j < 4; ++j) {
        int i = base + j;
        if (i < N_NODES) s += cnt[i];
    }
    lds[t] = s;
    __syncthreads();
    for (int off = 128; off > 0; off >>= 1) {
        if (t < off) lds[t] += lds[t + off];
        __syncthreads();
    }
    if (t == 0) bsum[b] = lds[0];
}

__global__ void k_scan2(int* __restrict__ bsum, int nb) {
    if (threadIdx.x == 0 && blockIdx.x == 0) {
        int acc = 0;
        for (int i = 0; i < nb; ++i) { int v = bsum[i]; bsum[i] = acc; acc += v; }
    }
}

__global__ void k_scan3(const int* __restrict__ cnt, const int* __restrict__ bsum,
                        int* __restrict__ row_ptr) {
    __shared__ int lds[256];
    int b = blockIdx.x, t = threadIdx.x;
    int base = b * SCAN_CHUNK + t * 4;
    int v[4];
    int s = 0;
#pragma unroll
    for (int j = 0; j < 4; ++j) {
        int i = base + j;
        v[j] = (i < N_NODES) ? cnt[i] : 0;
        s += v[j];
    }
    lds[t] = s;
    __syncthreads();
    for (int off = 1; off < 256; off <<= 1) {
        int add = (t >= off) ? lds[t - off] : 0;
        __syncthreads();
        lds[t] += add;
        __syncthreads();
    }
    int ex = bsum[b] + ((t > 0) ? lds[t - 1] : 0);
#pragma unroll
    for (int j = 0; j < 4; ++j) {
        int i = base + j;
        if (i < N_NODES) { ex += v[j]; row_ptr[i + 1] = ex; }
    }
    if (b == 0 && t == 0) row_ptr[0] = 0;
}

__global__ void k_fill(const int* __restrict__ src, const int* __restrict__ dst,
                       const int* __restrict__ row_ptr, int* __restrict__ fill,
                       int* __restrict__ col) {
    int e = blockIdx.x * blockDim.x + threadIdx.x;
    if (e < N_EDGES) {
        int d = dst[e];
        int pos = atomicAdd(&fill[d], 1);
        col[row_ptr[d] + pos] = src[e];
    }
}

// ---------------------------------------------------------------------------
// Aggregation only: mean[node][0..FIN) (stride 64) = mean over neighbors of h
// One wave owns NC contiguous nodes; row_ptr for all of them loaded in ONE
// lane-parallel load. No LDS, low VGPR -> high occupancy, deep gather MLP.
// ---------------------------------------------------------------------------
#define NC 16

template <int FIN>
__global__ __launch_bounds__(256) void k_agg(
    const float* __restrict__ h, const int* __restrict__ row_ptr,
    const int* __restrict__ col, float* __restrict__ mean) {
    int lane = threadIdx.x & 63;
    int wave = blockIdx.x * 4 + (threadIdx.x >> 6);
    int base = wave * NC;
    if (base >= N_NODES) return;
    // lanes 0..NC hold row_ptr[base+lane]
    int rp = row_ptr[base + (lane < NC ? lane : NC)];

    for (int i = 0; i < NC; ++i) {
        int node = base + i;
        int start = __shfl(rp, i);
        int end   = __shfl(rp, i + 1);
        float s = 0.0f;

        if constexpr (FIN == 64) {
            for (int eb = start; eb < end; eb += 64) {
                int n = end - eb; if (n > 64) n = 64;
                int c = (eb + lane < end) ? col[eb + lane] : 0;
                int j = 0;
                for (; j + 7 < n; j += 8) {
                    int c0 = __shfl(c, j),     c1 = __shfl(c, j + 1);
                    int c2 = __shfl(c, j + 2), c3 = __shfl(c, j + 3);
                    int c4 = __shfl(c, j + 4), c5 = __shfl(c, j + 5);
                    int c6 = __shfl(c, j + 6), c7 = __shfl(c, j + 7);
                    float a0 = h[c0 * 64 + lane], a1 = h[c1 * 64 + lane];
                    float a2 = h[c2 * 64 + lane], a3 = h[c3 * 64 + lane];
                    float a4 = h[c4 * 64 + lane], a5 = h[c5 * 64 + lane];
                    float a6 = h[c6 * 64 + lane], a7 = h[c7 * 64 + lane];
                    s += ((a0 + a1) + (a2 + a3)) + ((a4 + a5) + (a6 + a7));
                }
                for (; j + 3 < n; j += 4) {
                    int c0 = __shfl(c, j),     c1 = __shfl(c, j + 1);
                    int c2 = __shfl(c, j + 2), c3 = __shfl(c, j + 3);
                    float a0 = h[c0 * 64 + lane], a1 = h[c1 * 64 + lane];
                    float a2 = h[c2 * 64 + lane], a3 = h[c3 * 64 + lane];
                    s += (a0 + a1) + (a2 + a3);
                }
                for (; j < n; ++j) {
                    int cc = __shfl(c, j);
                    s += h[cc * 64 + lane];
                }
            }
        } else {  // FIN == 32: halves of the wave take alternating edges
            int k = lane & 31;
            int half = lane >> 5;
            for (int eb = start; eb < end; eb += 64) {
                int n = end - eb; if (n > 64) n = 64;
                int c = (eb + lane < end) ? col[eb + lane] : 0;
                int j = 0;
                for (; j + 7 < n; j += 8) {
                    int c0 = __shfl(c, j + half);
                    int c1 = __shfl(c, j + 2 + half);
                    int c2 = __shfl(c, j + 4 + half);
                    int c3 = __shfl(c, j + 6 + half);
                    float a0 = h[c0 * 32 + k], a1 = h[c1 * 32 + k];
                    float a2 = h[c2 * 32 + k], a3 = h[c3 * 32 + k];
                    s += (a0 + a1) + (a2 + a3);
                }
                for (; j < n; j += 2) {
                    if (j + half < n) {
                        int cc = __shfl(c, j + half);
                        s += h[cc * 32 + k];
                    }
                }
            }
            s += __shfl_xor(s, 32);
        }

        int deg = end - start;
        float m = (deg > 0) ? s / (float)deg : 0.0f;
        if (FIN == 64 || lane < 32) mean[node * 64 + (FIN == 64 ? lane : (lane & 31))] = m;
    }
}

// ---------------------------------------------------------------------------
// Dense transform: out[node][f] = sum_k mean[node][k]*Wl[k][f]
//                              +  sum_k x[node][k]*Wr[k][f]  + bl[f]
// R5 analysis: the allocator refuses 128 register-resident weights (spills to
// scratch); uniform row loads are latency-bound. New structure:
//  - lane f holds ITS OWN element of each node row (coalesced loads):
//      vm[i] = mean[(base+i)*64 + lane]
//  - node-uniform broadcast mean[k] via v_readlane -> SGPR, used as the
//    scalar operand of v_fmac_f32 (no LDS, no bpermute)
//  - weight row W[k][*] read once per k from LDS (ds_read_b32, 2-way bank =
//    free) and reused for 8 register-blocked nodes -> LDS traffic /8.
// Per node: 128 FMA + 128 readlane = 512 SIMD-cyc -> ~21us/layer predicted.
// In-place safe (out may alias mean or x): a wave fully reads its 8 nodes'
// rows before storing them, and nodes are owned by exactly one wave.
// ---------------------------------------------------------------------------
#define DB 8  // nodes per wave-iteration

template <int FIN, int XS>
__global__ __launch_bounds__(256) void k_dense(
    const float* mean,            // stride 64, first FIN valid (may alias out)
    const float* x,               // stride XS (may alias out)
    const float* __restrict__ Wl, const float* __restrict__ bl,
    const float* __restrict__ Wr, float* out) {
    __shared__ float wls[FIN * 64];
    __shared__ float wrs[FIN * 64];
    for (int i = threadIdx.x; i < FIN * 16; i += 256) {
        ((float4*)wls)[i] = ((const float4*)Wl)[i];
        ((float4*)wrs)[i] = ((const float4*)Wr)[i];
    }
    __syncthreads();

    int lane = threadIdx.x & 63;
    int wave = blockIdx.x * 4 + (threadIdx.x >> 6);
    int nWaves = gridDim.x * 4;
    float blf = bl[lane];

    int ml = (FIN == 64) ? lane : (lane & 31);
    int xl = (XS == 64) ? lane : (lane & 31);

    for (int base = wave * DB; base < N_NODES; base += nWaves * DB) {
        float vm[DB], vx[DB], acc[DB];
#pragma unroll
        for (int i = 0; i < DB; ++i) {
            int node = base + i;
            if (node < N_NODES) {
                vm[i] = mean[(size_t)node * 64 + ml];
                vx[i] = x[(size_t)node * XS + xl];
            } else {
                vm[i] = 0.0f; vx[i] = 0.0f;
            }
            acc[i] = blf;
        }
#pragma unroll
        for (int k = 0; k < FIN; ++k) {
            float w = wls[k * 64 + lane];
#pragma unroll
            for (int i = 0; i < DB; ++i) {
                acc[i] = fmaf(bcast_lane(vm[i], k), w, acc[i]);
            }
        }
#pragma unroll
        for (int k = 0; k < XS; ++k) {
            float w = wrs[k * 64 + lane];
#pragma unroll
            for (int i = 0; i < DB; ++i) {
                acc[i] = fmaf(bcast_lane(vx[i], k), w, acc[i]);
            }
        }
#pragma unroll
        for (int i = 0; i < DB; ++i) {
            int node = base + i;
            if (node < N_NODES) out[(size_t)node * 64 + lane] = acc[i];
        }
    }
}

__global__ __launch_bounds__(256) void k_pool(const float* __restrict__ h,
                                              const int* __restrict__ batch,
                                              float* __restrict__ pooled) {
    int lane = threadIdx.x & 63;
    int wave = (blockIdx.x * blockDim.x + threadIdx.x) >> 6;
    int nWaves = (gridDim.x * blockDim.x) >> 6;
    int per = (N_NODES + nWaves - 1) / nWaves;
    int beg = wave * per;
    int end = beg + per; if (end > N_NODES) end = N_NODES;
    if (beg >= end) return;
    int curg = batch[beg];
    float m = -INFINITY;
    for (int i = beg; i < end; ++i) {
        int g = batch[i];
        if (g != curg) {
            atomicMaxFloat(&pooled[curg * 64 + lane], m);
            m = -INFINITY;
            curg = g;
        }
        m = fmaxf(m, h[(size_t)i * 64 + lane]);
    }
    atomicMaxFloat(&pooled[curg * 64 + lane], m);
}

__global__ void k_head(const float* __restrict__ pooled,
                       const float* __restrict__ Wout,
                       const float* __restrict__ bout, float* __restrict__ out) {
    int tid = threadIdx.x;          // 512 threads: g = tid>>3, o = tid&7
    int g = tid >> 3, o = tid & 7;
    float acc = bout[o];
#pragma unroll
    for (int k = 0; k < 64; ++k) acc += pooled[g * 64 + k] * Wout[k * 8 + o];
    float mx = acc;
#pragma unroll
    for (int m = 1; m < 8; m <<= 1) mx = fmaxf(mx, __shfl_xor(mx, m));
    float ex = expf(acc - mx);
    float sum = ex;
#pragma unroll
    for (int m = 1; m < 8; m <<= 1) sum += __shfl_xor(sum, m);
    out[g * 8 + o] = (acc - mx) - logf(sum);
}

extern "C" void kernel_launch(void* const* d_in, const int* in_sizes, int n_in,
                              void* d_out, int out_size, void* d_ws, size_t ws_size,
                              hipStream_t stream) {
    const float* x    = (const float*)d_in[0];
    const float* Wl0  = (const float*)d_in[1];
    const float* bl0  = (const float*)d_in[2];
    const float* Wr0  = (const float*)d_in[3];
    const float* Wl1  = (const float*)d_in[4];
    const float* bl1  = (const float*)d_in[5];
    const float* Wr1  = (const float*)d_in[6];
    const float* Wl2  = (const float*)d_in[7];
    const float* bl2  = (const float*)d_in[8];
    const float* Wr2  = (const float*)d_in[9];
    const float* Wout = (const float*)d_in[10];
    const float* bout = (const float*)d_in[11];
    const int*   eidx = (const int*)d_in[12];
    const int*   batch= (const int*)d_in[13];
    const int* src = eidx;
    const int* dst = eidx + N_EDGES;

    uint8_t* ws = (uint8_t*)d_ws;
    int*   cnt     = (int*)(ws + 0);
    int*   fill    = (int*)(ws + 400128);
    int*   row_ptr = (int*)(ws + 800256);
    int*   col     = (int*)(ws + 1200384);
    float* pooled  = (float*)(ws + 7600384);
    int*   bsum    = (int*)(ws + 7616768);
    float* M       = (float*)(ws + 7617408);
    float* A       = (float*)(ws + 33217408);

    int nb = (N_NODES + SCAN_CHUNK - 1) / SCAN_CHUNK;  // 98

    k_init<<<(N_NODES + 255) / 256, 256, 0, stream>>>(cnt, fill, pooled);
    k_hist<<<(N_EDGES + 255) / 256, 256, 0, stream>>>(dst, cnt);
    k_scan1<<<nb, 256, 0, stream>>>(cnt, bsum);
    k_scan2<<<1, 64, 0, stream>>>(bsum, nb);
    k_scan3<<<nb, 256, 0, stream>>>(cnt, bsum, row_ptr);
    k_fill<<<(N_EDGES + 255) / 256, 256, 0, stream>>>(src, dst, row_ptr, fill, col);

    int aggBlocks = (N_NODES / NC + 3) / 4;    // 1563
    int denseBlocks = (N_NODES + 4 * DB - 1) / (4 * DB) / 2 + 1;  // ~2 iters/wave
    // ensure coverage: waves*DB*iters >= N_NODES; grid-stride handles rest
    denseBlocks = 1563;

    // layer 0: mean0 -> M (stride 64), h1 = dense in-place -> M
    k_agg<32><<<aggBlocks, 256, 0, stream>>>(x, row_ptr, col, M);
    k_dense<32, 32><<<denseBlocks, 256, 0, stream>>>(M, x, Wl0, bl0, Wr0, M);
    // layer 1: mean1 -> A, h2 in-place -> A
    k_agg<64><<<aggBlocks, 256, 0, stream>>>(M, row_ptr, col, A);
    k_dense<64, 64><<<denseBlocks, 256, 0, stream>>>(A, M, Wl1, bl1, Wr1, A);
    // layer 2: mean2 -> M, h3 in-place -> M
    k_agg<64><<<aggBlocks, 256, 0, stream>>>(A, row_ptr, col, M);
    k_dense<64, 64><<<denseBlocks, 256, 0, stream>>>(M, A, Wl2, bl2, Wr2, M);

    k_pool<<<256, 256, 0, stream>>>(M, batch, pooled);
    k_head<<<1, 512, 0, stream>>>(pooled, Wout, bout, (float*)d_out);
}

// Round 7
// 448.202 us; speedup vs baseline: 1.6467x; 1.4978x over previous
//
#include <hip/hip_runtime.h>
#include <math.h>
#include <stdint.h>

#define N_NODES 100000
#define N_EDGES 1600000
#define N_GRAPHS 64

// ---------------- workspace layout (bytes) ----------------
// cnt     @ 0        : 100000 int
// fill    @ 400128   : 100000 int
// row_ptr @ 800256   : 100001 int
// col     @ 1200384  : 1600000 int (6.4 MB)
// pooled  @ 7600384  : 64*64 float
// bsum    @ 7616768  : 128 int
// M       @ 7617408  : 100000*64 float (25.6 MB)   mean / h (in-place)
// A       @ 33217408 : 100000*64 float (25.6 MB)
// total ~58.8 MB

typedef __attribute__((ext_vector_type(8))) short bf16x8;
typedef __attribute__((ext_vector_type(4))) float f32x4;

__device__ __forceinline__ void atomicMaxFloat(float* addr, float val) {
    if (val >= 0.0f) {
        atomicMax((int*)addr, __float_as_int(val));
    } else {
        atomicMin((unsigned int*)addr, __float_as_uint(val));
    }
}

__device__ __forceinline__ short f2bf(float f) {   // RNE fp32 -> bf16 bits
    unsigned u = __float_as_uint(f);
    unsigned r = (u + 0x7FFFu + ((u >> 16) & 1u)) >> 16;
    return (short)r;
}
__device__ __forceinline__ float bf2f(short b) {
    return __uint_as_float(((unsigned)(unsigned short)b) << 16);
}

__global__ void k_init(int* __restrict__ cnt, int* __restrict__ fill,
                       float* __restrict__ pooled) {
    int i = blockIdx.x * blockDim.x + threadIdx.x;
    if (i < N_NODES) { cnt[i] = 0; fill[i] = 0; }
    if (i < N_GRAPHS * 64) pooled[i] = -INFINITY;
}

__global__ void k_hist(const int* __restrict__ dst, int* __restrict__ cnt) {
    int e = blockIdx.x * blockDim.x + threadIdx.x;
    if (e < N_EDGES) atomicAdd(&cnt[dst[e]], 1);
}

#define SCAN_CHUNK 1024

__global__ void k_scan1(const int* __restrict__ cnt, int* __restrict__ bsum) {
    __shared__ int lds[256];
    int b = blockIdx.x, t = threadIdx.x;
    int base = b * SCAN_CHUNK + t * 4;
    int s = 0;
#pragma unroll
    for (int j = 0; j < 4; ++j) {
        int i = base + j;
        if (i < N_NODES) s += cnt[i];
    }
    lds[t] = s;
    __syncthreads();
    for (int off = 128; off > 0; off >>= 1) {
        if (t < off) lds[t] += lds[t + off];
        __syncthreads();
    }
    if (t == 0) bsum[b] = lds[0];
}

__global__ void k_scan2(int* __restrict__ bsum, int nb) {
    if (threadIdx.x == 0 && blockIdx.x == 0) {
        int acc = 0;
        for (int i = 0; i < nb; ++i) { int v = bsum[i]; bsum[i] = acc; acc += v; }
    }
}

__global__ void k_scan3(const int* __restrict__ cnt, const int* __restrict__ bsum,
                        int* __restrict__ row_ptr) {
    __shared__ int lds[256];
    int b = blockIdx.x, t = threadIdx.x;
    int base = b * SCAN_CHUNK + t * 4;
    int v[4];
    int s = 0;
#pragma unroll
    for (int j = 0; j < 4; ++j) {
        int i = base + j;
        v[j] = (i < N_NODES) ? cnt[i] : 0;
        s += v[j];
    }
    lds[t] = s;
    __syncthreads();
    for (int off = 1; off < 256; off <<= 1) {
        int add = (t >= off) ? lds[t - off] : 0;
        __syncthreads();
        lds[t] += add;
        __syncthreads();
    }
    int ex = bsum[b] + ((t > 0) ? lds[t - 1] : 0);
#pragma unroll
    for (int j = 0; j < 4; ++j) {
        int i = base + j;
        if (i < N_NODES) { ex += v[j]; row_ptr[i + 1] = ex; }
    }
    if (b == 0 && t == 0) row_ptr[0] = 0;
}

__global__ void k_fill(const int* __restrict__ src, const int* __restrict__ dst,
                       const int* __restrict__ row_ptr, int* __restrict__ fill,
                       int* __restrict__ col) {
    int e = blockIdx.x * blockDim.x + threadIdx.x;
    if (e < N_EDGES) {
        int d = dst[e];
        int pos = atomicAdd(&fill[d], 1);
        col[row_ptr[d] + pos] = src[e];
    }
}

// ---------------------------------------------------------------------------
// Aggregation only: mean[node][0..FIN) (stride 64) = mean over neighbors of h
// ---------------------------------------------------------------------------
#define NC 16

template <int FIN>
__global__ __launch_bounds__(256) void k_agg(
    const float* __restrict__ h, const int* __restrict__ row_ptr,
    const int* __restrict__ col, float* __restrict__ mean) {
    int lane = threadIdx.x & 63;
    int wave = blockIdx.x * 4 + (threadIdx.x >> 6);
    int base = wave * NC;
    if (base >= N_NODES) return;
    int rp = row_ptr[base + (lane < NC ? lane : NC)];

    for (int i = 0; i < NC; ++i) {
        int node = base + i;
        int start = __shfl(rp, i);
        int end   = __shfl(rp, i + 1);
        float s = 0.0f;

        if constexpr (FIN == 64) {
            for (int eb = start; eb < end; eb += 64) {
                int n = end - eb; if (n > 64) n = 64;
                int c = (eb + lane < end) ? col[eb + lane] : 0;
                int j = 0;
                for (; j + 7 < n; j += 8) {
                    int c0 = __shfl(c, j),     c1 = __shfl(c, j + 1);
                    int c2 = __shfl(c, j + 2), c3 = __shfl(c, j + 3);
                    int c4 = __shfl(c, j + 4), c5 = __shfl(c, j + 5);
                    int c6 = __shfl(c, j + 6), c7 = __shfl(c, j + 7);
                    float a0 = h[c0 * 64 + lane], a1 = h[c1 * 64 + lane];
                    float a2 = h[c2 * 64 + lane], a3 = h[c3 * 64 + lane];
                    float a4 = h[c4 * 64 + lane], a5 = h[c5 * 64 + lane];
                    float a6 = h[c6 * 64 + lane], a7 = h[c7 * 64 + lane];
                    s += ((a0 + a1) + (a2 + a3)) + ((a4 + a5) + (a6 + a7));
                }
                for (; j + 3 < n; j += 4) {
                    int c0 = __shfl(c, j),     c1 = __shfl(c, j + 1);
                    int c2 = __shfl(c, j + 2), c3 = __shfl(c, j + 3);
                    float a0 = h[c0 * 64 + lane], a1 = h[c1 * 64 + lane];
                    float a2 = h[c2 * 64 + lane], a3 = h[c3 * 64 + lane];
                    s += (a0 + a1) + (a2 + a3);
                }
                for (; j < n; ++j) {
                    int cc = __shfl(c, j);
                    s += h[cc * 64 + lane];
                }
            }
        } else {  // FIN == 32
            int k = lane & 31;
            int half = lane >> 5;
            for (int eb = start; eb < end; eb += 64) {
                int n = end - eb; if (n > 64) n = 64;
                int c = (eb + lane < end) ? col[eb + lane] : 0;
                int j = 0;
                for (; j + 7 < n; j += 8) {
                    int c0 = __shfl(c, j + half);
                    int c1 = __shfl(c, j + 2 + half);
                    int c2 = __shfl(c, j + 4 + half);
                    int c3 = __shfl(c, j + 6 + half);
                    float a0 = h[c0 * 32 + k], a1 = h[c1 * 32 + k];
                    float a2 = h[c2 * 32 + k], a3 = h[c3 * 32 + k];
                    s += (a0 + a1) + (a2 + a3);
                }
                for (; j < n; j += 2) {
                    if (j + half < n) {
                        int cc = __shfl(c, j + half);
                        s += h[cc * 32 + k];
                    }
                }
            }
            s += __shfl_xor(s, 32);
        }

        int deg = end - start;
        float m = (deg > 0) ? s / (float)deg : 0.0f;
        if (FIN == 64 || lane < 32) mean[node * 64 + (FIN == 64 ? lane : (lane & 31))] = m;
    }
}

// ---------------------------------------------------------------------------
// Dense transform via MFMA (bf16 hi/lo split for ~fp32 activation accuracy):
//   out[node][f] = sum_k mean[node][k]*Wl[k][f] + sum_k x[node][k]*Wr[k][f] + bl[f]
// One wave per 16-node strip: 4 col-tiles of 16, K in 32-chunks.
// A-fragment: lane(l) row=l&15, k=(l>>4)*8+j  (j=0..7, two float4 loads)
// B-fragment: lane(l) col=l&15, k=(l>>4)*8+j  (same k-map -> permutation-proof)
// D: col=lane&15, row=(lane>>4)*4+reg  [m89-verified]
// Activations split v = hi + lo (bf16 each) -> 2 MFMAs per fragment.
// In-place safe: out aliases mean only; wave reads all its rows before store.
// ---------------------------------------------------------------------------
template <int KM, int KX, int XS>
__global__ __launch_bounds__(256) void k_dense_mfma(
    const float* mean,            // stride 64, first KM valid (aliases out)
    const float* x,               // stride XS
    const float* __restrict__ Wl, const float* __restrict__ bl,
    const float* __restrict__ Wr, float* out) {
    int lane = threadIdx.x & 63;
    int strip = blockIdx.x * 4 + (threadIdx.x >> 6);
    if (strip * 16 >= N_NODES) return;
    int row0 = strip * 16;
    int m = lane & 15;
    int g = lane >> 4;

    f32x4 acc[4] = {};

    // ---- mean @ Wl ----
#pragma unroll
    for (int kt = 0; kt < KM / 32; ++kt) {
        int k0 = kt * 32 + g * 8;
        const float4* ap = (const float4*)(mean + (size_t)(row0 + m) * 64 + k0);
        float4 a0 = ap[0], a1 = ap[1];
        float av[8] = {a0.x, a0.y, a0.z, a0.w, a1.x, a1.y, a1.z, a1.w};
        bf16x8 ahi, alo;
#pragma unroll
        for (int j = 0; j < 8; ++j) {
            short hb = f2bf(av[j]);
            ahi[j] = hb;
            alo[j] = f2bf(av[j] - bf2f(hb));
        }
#pragma unroll
        for (int nt = 0; nt < 4; ++nt) {
            bf16x8 b;
#pragma unroll
            for (int j = 0; j < 8; ++j)
                b[j] = f2bf(Wl[(size_t)(k0 + j) * 64 + nt * 16 + m]);
            acc[nt] = __builtin_amdgcn_mfma_f32_16x16x32_bf16(ahi, b, acc[nt], 0, 0, 0);
            acc[nt] = __builtin_amdgcn_mfma_f32_16x16x32_bf16(alo, b, acc[nt], 0, 0, 0);
        }
    }
    // ---- x @ Wr ----
#pragma unroll
    for (int kt = 0; kt < KX / 32; ++kt) {
        int k0 = kt * 32 + g * 8;
        const float4* ap = (const float4*)(x + (size_t)(row0 + m) * XS + k0);
        float4 a0 = ap[0], a1 = ap[1];
        float av[8] = {a0.x, a0.y, a0.z, a0.w, a1.x, a1.y, a1.z, a1.w};
        bf16x8 ahi, alo;
#pragma unroll
        for (int j = 0; j < 8; ++j) {
            short hb = f2bf(av[j]);
            ahi[j] = hb;
            alo[j] = f2bf(av[j] - bf2f(hb));
        }
#pragma unroll
        for (int nt = 0; nt < 4; ++nt) {
            bf16x8 b;
#pragma unroll
            for (int j = 0; j < 8; ++j)
                b[j] = f2bf(Wr[(size_t)(k0 + j) * 64 + nt * 16 + m]);
            acc[nt] = __builtin_amdgcn_mfma_f32_16x16x32_bf16(ahi, b, acc[nt], 0, 0, 0);
            acc[nt] = __builtin_amdgcn_mfma_f32_16x16x32_bf16(alo, b, acc[nt], 0, 0, 0);
        }
    }
    // ---- bias + store ----
#pragma unroll
    for (int nt = 0; nt < 4; ++nt) {
        float bias = bl[nt * 16 + m];
#pragma unroll
        for (int r = 0; r < 4; ++r) {
            int row = row0 + g * 4 + r;
            out[(size_t)row * 64 + nt * 16 + m] = acc[nt][r] + bias;
        }
    }
}

__global__ __launch_bounds__(256) void k_pool(const float* __restrict__ h,
                                              const int* __restrict__ batch,
                                              float* __restrict__ pooled) {
    int lane = threadIdx.x & 63;
    int wave = (blockIdx.x * blockDim.x + threadIdx.x) >> 6;
    int nWaves = (gridDim.x * blockDim.x) >> 6;
    int per = (N_NODES + nWaves - 1) / nWaves;
    int beg = wave * per;
    int end = beg + per; if (end > N_NODES) end = N_NODES;
    if (beg >= end) return;
    int curg = batch[beg];
    float m = -INFINITY;
    for (int i = beg; i < end; ++i) {
        int g = batch[i];
        if (g != curg) {
            atomicMaxFloat(&pooled[curg * 64 + lane], m);
            m = -INFINITY;
            curg = g;
        }
        m = fmaxf(m, h[(size_t)i * 64 + lane]);
    }
    atomicMaxFloat(&pooled[curg * 64 + lane], m);
}

__global__ void k_head(const float* __restrict__ pooled,
                       const float* __restrict__ Wout,
                       const float* __restrict__ bout, float* __restrict__ out) {
    int tid = threadIdx.x;          // 512 threads: g = tid>>3, o = tid&7
    int g = tid >> 3, o = tid & 7;
    float acc = bout[o];
#pragma unroll
    for (int k = 0; k < 64; ++k) acc += pooled[g * 64 + k] * Wout[k * 8 + o];
    float mx = acc;
#pragma unroll
    for (int m = 1; m < 8; m <<= 1) mx = fmaxf(mx, __shfl_xor(mx, m));
    float ex = expf(acc - mx);
    float sum = ex;
#pragma unroll
    for (int m = 1; m < 8; m <<= 1) sum += __shfl_xor(sum, m);
    out[g * 8 + o] = (acc - mx) - logf(sum);
}

extern "C" void kernel_launch(void* const* d_in, const int* in_sizes, int n_in,
                              void* d_out, int out_size, void* d_ws, size_t ws_size,
                              hipStream_t stream) {
    const float* x    = (const float*)d_in[0];
    const float* Wl0  = (const float*)d_in[1];
    const float* bl0  = (const float*)d_in[2];
    const float* Wr0  = (const float*)d_in[3];
    const float* Wl1  = (const float*)d_in[4];
    const float* bl1  = (const float*)d_in[5];
    const float* Wr1  = (const float*)d_in[6];
    const float* Wl2  = (const float*)d_in[7];
    const float* bl2  = (const float*)d_in[8];
    const float* Wr2  = (const float*)d_in[9];
    const float* Wout = (const float*)d_in[10];
    const float* bout = (const float*)d_in[11];
    const int*   eidx = (const int*)d_in[12];
    const int*   batch= (const int*)d_in[13];
    const int* src = eidx;
    const int* dst = eidx + N_EDGES;

    uint8_t* ws = (uint8_t*)d_ws;
    int*   cnt     = (int*)(ws + 0);
    int*   fill    = (int*)(ws + 400128);
    int*   row_ptr = (int*)(ws + 800256);
    int*   col     = (int*)(ws + 1200384);
    float* pooled  = (float*)(ws + 7600384);
    int*   bsum    = (int*)(ws + 7616768);
    float* M       = (float*)(ws + 7617408);
    float* A       = (float*)(ws + 33217408);

    int nb = (N_NODES + SCAN_CHUNK - 1) / SCAN_CHUNK;  // 98

    k_init<<<(N_NODES + 255) / 256, 256, 0, stream>>>(cnt, fill, pooled);
    k_hist<<<(N_EDGES + 255) / 256, 256, 0, stream>>>(dst, cnt);
    k_scan1<<<nb, 256, 0, stream>>>(cnt, bsum);
    k_scan2<<<1, 64, 0, stream>>>(bsum, nb);
    k_scan3<<<nb, 256, 0, stream>>>(cnt, bsum, row_ptr);
    k_fill<<<(N_EDGES + 255) / 256, 256, 0, stream>>>(src, dst, row_ptr, fill, col);

    int aggBlocks = (N_NODES / NC + 3) / 4;        // 1563
    int mfmaBlocks = (N_NODES / 16 + 3) / 4;       // 1563 (6250 strips)

    // layer 0: mean0 -> M (stride 64, 32 valid), h1 = dense in-place -> M
    k_agg<32><<<aggBlocks, 256, 0, stream>>>(x, row_ptr, col, M);
    k_dense_mfma<32, 32, 32><<<mfmaBlocks, 256, 0, stream>>>(M, x, Wl0, bl0, Wr0, M);
    // layer 1: mean1 -> A, h2 in-place -> A
    k_agg<64><<<aggBlocks, 256, 0, stream>>>(M, row_ptr, col, A);
    k_dense_mfma<64, 64, 64><<<mfmaBlocks, 256, 0, stream>>>(A, M, Wl1, bl1, Wr1, A);
    // layer 2: mean2 -> M, h3 in-place -> M
    k_agg<64><<<aggBlocks, 256, 0, stream>>>(A, row_ptr, col, M);
    k_dense_mfma<64, 64, 64><<<mfmaBlocks, 256, 0, stream>>>(M, A, Wl2, bl2, Wr2, M);

    k_pool<<<256, 256, 0, stream>>>(M, batch, pooled);
    k_head<<<1, 512, 0, stream>>>(pooled, Wout, bout, (float*)d_out);
}

// Round 8
// 412.827 us; speedup vs baseline: 1.7878x; 1.0857x over previous
//
#include <hip/hip_runtime.h>
#include <math.h>
#include <stdint.h>

#define N_NODES 100000
#define N_EDGES 1600000
#define N_GRAPHS 64
#define NPART 8
#define PART_SZ 12500   // N_NODES / NPART

// ---------------- workspace layout (bytes) ----------------
// cnt     @ 0        : 100000 int
// fill    @ 400128   : 100000 int
// row_ptr @ 800256   : 100001 int
// col     @ 1200384  : 1600000 int (6.4 MB)
// pooled  @ 7600384  : 64*64 float
// bsum    @ 7616768  : 128 int
// M       @ 7617408  : 100000*64 fp32 (25.6 MB)  means / final h (in-place)
// Hhi     @ 33217408 : 100000*64 bf16 (12.8 MB)  hi plane (layer0: x-hi, stride 32)
// Hlo     @ 46017408 : 100000*64 bf16 (12.8 MB)  lo plane
// total ~58.8 MB (same as R7 footprint)

typedef __attribute__((ext_vector_type(8))) short bf16x8;
typedef __attribute__((ext_vector_type(8))) unsigned short u16x8;
typedef __attribute__((ext_vector_type(4))) float f32x4;

__device__ __forceinline__ void atomicMaxFloat(float* addr, float val) {
    if (val >= 0.0f) {
        atomicMax((int*)addr, __float_as_int(val));
    } else {
        atomicMin((unsigned int*)addr, __float_as_uint(val));
    }
}

__device__ __forceinline__ unsigned short f2bf(float f) {   // RNE fp32 -> bf16
    unsigned u = __float_as_uint(f);
    unsigned r = (u + 0x7FFFu + ((u >> 16) & 1u)) >> 16;
    return (unsigned short)r;
}
__device__ __forceinline__ float bf2f(unsigned short b) {
    return __uint_as_float(((unsigned)b) << 16);
}

__global__ void k_init(int* __restrict__ cnt, int* __restrict__ fill,
                       float* __restrict__ pooled) {
    int i = blockIdx.x * blockDim.x + threadIdx.x;
    if (i < N_NODES) { cnt[i] = 0; fill[i] = 0; }
    if (i < N_GRAPHS * 64) pooled[i] = -INFINITY;
}

__global__ void k_hist(const int* __restrict__ dst, int* __restrict__ cnt) {
    int e = blockIdx.x * blockDim.x + threadIdx.x;
    if (e < N_EDGES) atomicAdd(&cnt[dst[e]], 1);
}

#define SCAN_CHUNK 1024

__global__ void k_scan1(const int* __restrict__ cnt, int* __restrict__ bsum) {
    __shared__ int lds[256];
    int b = blockIdx.x, t = threadIdx.x;
    int base = b * SCAN_CHUNK + t * 4;
    int s = 0;
#pragma unroll
    for (int j = 0; j < 4; ++j) {
        int i = base + j;
        if (i < N_NODES) s += cnt[i];
    }
    lds[t] = s;
    __syncthreads();
    for (int off = 128; off > 0; off >>= 1) {
        if (t < off) lds[t] += lds[t + off];
        __syncthreads();
    }
    if (t == 0) bsum[b] = lds[0];
}

__global__ void k_scan2(int* __restrict__ bsum, int nb) {
    if (threadIdx.x == 0 && blockIdx.x == 0) {
        int acc = 0;
        for (int i = 0; i < nb; ++i) { int v = bsum[i]; bsum[i] = acc; acc += v; }
    }
}

__global__ void k_scan3(const int* __restrict__ cnt, const int* __restrict__ bsum,
                        int* __restrict__ row_ptr) {
    __shared__ int lds[256];
    int b = blockIdx.x, t = threadIdx.x;
    int base = b * SCAN_CHUNK + t * 4;
    int v[4];
    int s = 0;
#pragma unroll
    for (int j = 0; j < 4; ++j) {
        int i = base + j;
        v[j] = (i < N_NODES) ? cnt[i] : 0;
        s += v[j];
    }
    lds[t] = s;
    __syncthreads();
    for (int off = 1; off < 256; off <<= 1) {
        int add = (t >= off) ? lds[t - off] : 0;
        __syncthreads();
        lds[t] += add;
        __syncthreads();
    }
    int ex = bsum[b] + ((t > 0) ? lds[t - 1] : 0);
#pragma unroll
    for (int j = 0; j < 4; ++j) {
        int i = base + j;
        if (i < N_NODES) { ex += v[j]; row_ptr[i + 1] = ex; }
    }
    if (b == 0 && t == 0) row_ptr[0] = 0;
}

// ---------------------------------------------------------------------------
// XCD-partitioned CSR fill. R7 profile: plain scatter fill wrote 107 MB to
// HBM (each 64B col line ping-pongs between non-coherent per-XCD L2s).
// Blocks with blockIdx%8==p land on XCD p (round-robin heuristic) and own
// dst range [p*12500,(p+1)*12500): col writes for a partition stay in ONE
// L2 -> written back once. Edges re-read 8x from L2/L3 (cheap).
// ---------------------------------------------------------------------------
__global__ __launch_bounds__(256) void k_fill_part(
    const int* __restrict__ src, const int* __restrict__ dst,
    const int* __restrict__ row_ptr, int* __restrict__ fill,
    int* __restrict__ col) {
    int p = blockIdx.x & (NPART - 1);
    int chunk = blockIdx.x >> 3;
    int nchunk = gridDim.x >> 3;
    int lo = p * PART_SZ, hi = lo + PART_SZ;
    for (int e = chunk * 256 + threadIdx.x; e < N_EDGES; e += nchunk * 256) {
        int d = dst[e];
        if (d >= lo && d < hi) {
            int pos = atomicAdd(&fill[d], 1);
            col[row_ptr[d] + pos] = src[e];
        }
    }
}

// Convert input x (fp32, stride 32) -> bf16 hi plane (stride 32) for gathers.
__global__ void k_xcast(const float* __restrict__ x, unsigned short* __restrict__ xhi) {
    int i = blockIdx.x * blockDim.x + threadIdx.x;   // one u16x8 per thread
    int base = i * 8;
    if (base >= N_NODES * 32) return;
    const float4* xp = (const float4*)(x + base);
    float4 a = xp[0], b = xp[1];
    u16x8 o;
    o[0] = f2bf(a.x); o[1] = f2bf(a.y); o[2] = f2bf(a.z); o[3] = f2bf(a.w);
    o[4] = f2bf(b.x); o[5] = f2bf(b.y); o[6] = f2bf(b.z); o[7] = f2bf(b.w);
    *(u16x8*)(xhi + base) = o;
}

// ---------------------------------------------------------------------------
// Aggregation from the bf16 HI plane: mean[node][k] (fp32, stride 64).
// Gathers read 2B/lane (128B/neighbor for FIN=64) -> half the R7 traffic.
// ---------------------------------------------------------------------------
#define NC 16

template <int FIN>
__global__ __launch_bounds__(256) void k_agg_bf(
    const unsigned short* __restrict__ hb,   // stride FIN
    const int* __restrict__ row_ptr, const int* __restrict__ col,
    float* __restrict__ mean) {
    int lane = threadIdx.x & 63;
    int wave = blockIdx.x * 4 + (threadIdx.x >> 6);
    int base = wave * NC;
    if (base >= N_NODES) return;
    int rp = row_ptr[base + (lane < NC ? lane : NC)];

    for (int i = 0; i < NC; ++i) {
        int node = base + i;
        int start = __shfl(rp, i);
        int end   = __shfl(rp, i + 1);
        float s = 0.0f;

        if constexpr (FIN == 64) {
            for (int eb = start; eb < end; eb += 64) {
                int n = end - eb; if (n > 64) n = 64;
                int c = (eb + lane < end) ? col[eb + lane] : 0;
                int j = 0;
                for (; j + 7 < n; j += 8) {
                    int c0 = __shfl(c, j),     c1 = __shfl(c, j + 1);
                    int c2 = __shfl(c, j + 2), c3 = __shfl(c, j + 3);
                    int c4 = __shfl(c, j + 4), c5 = __shfl(c, j + 5);
                    int c6 = __shfl(c, j + 6), c7 = __shfl(c, j + 7);
                    float a0 = bf2f(hb[(size_t)c0 * 64 + lane]);
                    float a1 = bf2f(hb[(size_t)c1 * 64 + lane]);
                    float a2 = bf2f(hb[(size_t)c2 * 64 + lane]);
                    float a3 = bf2f(hb[(size_t)c3 * 64 + lane]);
                    float a4 = bf2f(hb[(size_t)c4 * 64 + lane]);
                    float a5 = bf2f(hb[(size_t)c5 * 64 + lane]);
                    float a6 = bf2f(hb[(size_t)c6 * 64 + lane]);
                    float a7 = bf2f(hb[(size_t)c7 * 64 + lane]);
                    s += ((a0 + a1) + (a2 + a3)) + ((a4 + a5) + (a6 + a7));
                }
                for (; j < n; ++j) {
                    int cc = __shfl(c, j);
                    s += bf2f(hb[(size_t)cc * 64 + lane]);
                }
            }
        } else {  // FIN == 32: halves take alternating edges
            int k = lane & 31;
            int half = lane >> 5;
            for (int eb = start; eb < end; eb += 64) {
                int n = end - eb; if (n > 64) n = 64;
                int c = (eb + lane < end) ? col[eb + lane] : 0;
                int j = 0;
                for (; j + 7 < n; j += 8) {
                    int c0 = __shfl(c, j + half);
                    int c1 = __shfl(c, j + 2 + half);
                    int c2 = __shfl(c, j + 4 + half);
                    int c3 = __shfl(c, j + 6 + half);
                    float a0 = bf2f(hb[(size_t)c0 * 32 + k]);
                    float a1 = bf2f(hb[(size_t)c1 * 32 + k]);
                    float a2 = bf2f(hb[(size_t)c2 * 32 + k]);
                    float a3 = bf2f(hb[(size_t)c3 * 32 + k]);
                    s += (a0 + a1) + (a2 + a3);
                }
                for (; j < n; j += 2) {
                    if (j + half < n) {
                        int cc = __shfl(c, j + half);
                        s += bf2f(hb[(size_t)cc * 32 + k]);
                    }
                }
            }
            s += __shfl_xor(s, 32);
        }

        int deg = end - start;
        float m = (deg > 0) ? s / (float)deg : 0.0f;
        if (FIN == 64 || lane < 32) mean[node * 64 + (FIN == 64 ? lane : (lane & 31))] = m;
    }
}

// ---------------------------------------------------------------------------
// Dense transform via MFMA:
//   out = mean @ Wl + bl + h @ Wr
// A-path: mean fp32 (split hi/lo on the fly).
// X-path: XBF ? (Hhi,Hlo planes loaded directly as bf16x8 MFMA operands)
//             : fp32 x split on the fly (layer 0).
// Output: OUTBF ? (hi,lo bf16 planes) : fp32 (layer 2, feeds pool).
// In-place safe: each row is read only by its owning wave, fully, pre-store.
// ---------------------------------------------------------------------------
template <int KM, bool XBF, int KX, int XS, bool OUTBF>
__global__ __launch_bounds__(256) void k_dense_mfma(
    const float* mean,                        // stride 64, may alias out
    const float* x,                           // fp32 path (XBF=false)
    const unsigned short* xhi, const unsigned short* xlo,  // bf16 path
    const float* __restrict__ Wl, const float* __restrict__ bl,
    const float* __restrict__ Wr,
    float* outf, unsigned short* ohi, unsigned short* olo) {
    int lane = threadIdx.x & 63;
    int strip = blockIdx.x * 4 + (threadIdx.x >> 6);
    if (strip * 16 >= N_NODES) return;
    int row0 = strip * 16;
    int m = lane & 15;
    int g = lane >> 4;

    f32x4 acc[4] = {};

    // ---- mean @ Wl (fp32 -> hi/lo split) ----
#pragma unroll
    for (int kt = 0; kt < KM / 32; ++kt) {
        int k0 = kt * 32 + g * 8;
        const float4* ap = (const float4*)(mean + (size_t)(row0 + m) * 64 + k0);
        float4 a0 = ap[0], a1 = ap[1];
        float av[8] = {a0.x, a0.y, a0.z, a0.w, a1.x, a1.y, a1.z, a1.w};
        bf16x8 ahi, alo;
#pragma unroll
        for (int j = 0; j < 8; ++j) {
            unsigned short hb = f2bf(av[j]);
            ahi[j] = (short)hb;
            alo[j] = (short)f2bf(av[j] - bf2f(hb));
        }
#pragma unroll
        for (int nt = 0; nt < 4; ++nt) {
            bf16x8 b;
#pragma unroll
            for (int j = 0; j < 8; ++j)
                b[j] = (short)f2bf(Wl[(size_t)(k0 + j) * 64 + nt * 16 + m]);
            acc[nt] = __builtin_amdgcn_mfma_f32_16x16x32_bf16(ahi, b, acc[nt], 0, 0, 0);
            acc[nt] = __builtin_amdgcn_mfma_f32_16x16x32_bf16(alo, b, acc[nt], 0, 0, 0);
        }
    }
    // ---- h @ Wr ----
#pragma unroll
    for (int kt = 0; kt < KX / 32; ++kt) {
        int k0 = kt * 32 + g * 8;
        bf16x8 ahi, alo;
        if constexpr (XBF) {
            ahi = *(const bf16x8*)(xhi + (size_t)(row0 + m) * XS + k0);
            alo = *(const bf16x8*)(xlo + (size_t)(row0 + m) * XS + k0);
        } else {
            const float4* ap = (const float4*)(x + (size_t)(row0 + m) * XS + k0);
            float4 a0 = ap[0], a1 = ap[1];
            float av[8] = {a0.x, a0.y, a0.z, a0.w, a1.x, a1.y, a1.z, a1.w};
#pragma unroll
            for (int j = 0; j < 8; ++j) {
                unsigned short hb = f2bf(av[j]);
                ahi[j] = (short)hb;
                alo[j] = (short)f2bf(av[j] - bf2f(hb));
            }
        }
#pragma unroll
        for (int nt = 0; nt < 4; ++nt) {
            bf16x8 b;
#pragma unroll
            for (int j = 0; j < 8; ++j)
                b[j] = (short)f2bf(Wr[(size_t)(k0 + j) * 64 + nt * 16 + m]);
            acc[nt] = __builtin_amdgcn_mfma_f32_16x16x32_bf16(ahi, b, acc[nt], 0, 0, 0);
            acc[nt] = __builtin_amdgcn_mfma_f32_16x16x32_bf16(alo, b, acc[nt], 0, 0, 0);
        }
    }
    // ---- bias + store ----
#pragma unroll
    for (int nt = 0; nt < 4; ++nt) {
        float bias = bl[nt * 16 + m];
#pragma unroll
        for (int r = 0; r < 4; ++r) {
            int row = row0 + g * 4 + r;
            float v = acc[nt][r] + bias;
            if constexpr (OUTBF) {
                unsigned short hb = f2bf(v);
                ohi[(size_t)row * 64 + nt * 16 + m] = hb;
                olo[(size_t)row * 64 + nt * 16 + m] = f2bf(v - bf2f(hb));
            } else {
                outf[(size_t)row * 64 + nt * 16 + m] = v;
            }
        }
    }
}

__global__ __launch_bounds__(256) void k_pool(const float* __restrict__ h,
                                              const int* __restrict__ batch,
                                              float* __restrict__ pooled) {
    int lane = threadIdx.x & 63;
    int wave = (blockIdx.x * blockDim.x + threadIdx.x) >> 6;
    int nWaves = (gridDim.x * blockDim.x) >> 6;
    int per = (N_NODES + nWaves - 1) / nWaves;
    int beg = wave * per;
    int end = beg + per; if (end > N_NODES) end = N_NODES;
    if (beg >= end) return;
    int curg = batch[beg];
    float m = -INFINITY;
    for (int i = beg; i < end; ++i) {
        int g = batch[i];
        if (g != curg) {
            atomicMaxFloat(&pooled[curg * 64 + lane], m);
            m = -INFINITY;
            curg = g;
        }
        m = fmaxf(m, h[(size_t)i * 64 + lane]);
    }
    atomicMaxFloat(&pooled[curg * 64 + lane], m);
}

__global__ void k_head(const float* __restrict__ pooled,
                       const float* __restrict__ Wout,
                       const float* __restrict__ bout, float* __restrict__ out) {
    int tid = threadIdx.x;          // 512 threads: g = tid>>3, o = tid&7
    int g = tid >> 3, o = tid & 7;
    float acc = bout[o];
#pragma unroll
    for (int k = 0; k < 64; ++k) acc += pooled[g * 64 + k] * Wout[k * 8 + o];
    float mx = acc;
#pragma unroll
    for (int m = 1; m < 8; m <<= 1) mx = fmaxf(mx, __shfl_xor(mx, m));
    float ex = expf(acc - mx);
    float sum = ex;
#pragma unroll
    for (int m = 1; m < 8; m <<= 1) sum += __shfl_xor(sum, m);
    out[g * 8 + o] = (acc - mx) - logf(sum);
}

extern "C" void kernel_launch(void* const* d_in, const int* in_sizes, int n_in,
                              void* d_out, int out_size, void* d_ws, size_t ws_size,
                              hipStream_t stream) {
    const float* x    = (const float*)d_in[0];
    const float* Wl0  = (const float*)d_in[1];
    const float* bl0  = (const float*)d_in[2];
    const float* Wr0  = (const float*)d_in[3];
    const float* Wl1  = (const float*)d_in[4];
    const float* bl1  = (const float*)d_in[5];
    const float* Wr1  = (const float*)d_in[6];
    const float* Wl2  = (const float*)d_in[7];
    const float* bl2  = (const float*)d_in[8];
    const float* Wr2  = (const float*)d_in[9];
    const float* Wout = (const float*)d_in[10];
    const float* bout = (const float*)d_in[11];
    const int*   eidx = (const int*)d_in[12];
    const int*   batch= (const int*)d_in[13];
    const int* src = eidx;
    const int* dst = eidx + N_EDGES;

    uint8_t* ws = (uint8_t*)d_ws;
    int*   cnt     = (int*)(ws + 0);
    int*   fill    = (int*)(ws + 400128);
    int*   row_ptr = (int*)(ws + 800256);
    int*   col     = (int*)(ws + 1200384);
    float* pooled  = (float*)(ws + 7600384);
    int*   bsum    = (int*)(ws + 7616768);
    float* M       = (float*)(ws + 7617408);
    unsigned short* Hhi = (unsigned short*)(ws + 33217408);
    unsigned short* Hlo = (unsigned short*)(ws + 46017408);

    int nb = (N_NODES + SCAN_CHUNK - 1) / SCAN_CHUNK;  // 98

    k_init<<<(N_NODES + 255) / 256, 256, 0, stream>>>(cnt, fill, pooled);
    k_hist<<<(N_EDGES + 255) / 256, 256, 0, stream>>>(dst, cnt);
    k_scan1<<<nb, 256, 0, stream>>>(cnt, bsum);
    k_scan2<<<1, 64, 0, stream>>>(bsum, nb);
    k_scan3<<<nb, 256, 0, stream>>>(cnt, bsum, row_ptr);
    k_fill_part<<<NPART * 128, 256, 0, stream>>>(src, dst, row_ptr, fill, col);
    k_xcast<<<(N_NODES * 32 / 8 + 255) / 256, 256, 0, stream>>>(x, Hhi);

    int aggBlocks = (N_NODES / NC + 3) / 4;        // 1563
    int mfmaBlocks = (N_NODES / 16 + 3) / 4;       // 1563

    // layer 0: mean0 (from x-hi gathers) -> M; h1 -> Hhi/Hlo (overwrites x-hi)
    k_agg_bf<32><<<aggBlocks, 256, 0, stream>>>(Hhi, row_ptr, col, M);
    k_dense_mfma<32, false, 32, 32, true><<<mfmaBlocks, 256, 0, stream>>>(
        M, x, nullptr, nullptr, Wl0, bl0, Wr0, nullptr, Hhi, Hlo);
    // layer 1: mean1 (from h1-hi gathers) -> M; h2 -> Hhi/Hlo (in-place)
    k_agg_bf<64><<<aggBlocks, 256, 0, stream>>>(Hhi, row_ptr, col, M);
    k_dense_mfma<64, true, 64, 64, true><<<mfmaBlocks, 256, 0, stream>>>(
        M, nullptr, Hhi, Hlo, Wl1, bl1, Wr1, nullptr, Hhi, Hlo);
    // layer 2: mean2 -> M; h3 (fp32) -> M in-place; pool reads M
    k_agg_bf<64><<<aggBlocks, 256, 0, stream>>>(Hhi, row_ptr, col, M);
    k_dense_mfma<64, true, 64, 64, false><<<mfmaBlocks, 256, 0, stream>>>(
        M, nullptr, Hhi, Hlo, Wl2, bl2, Wr2, M, nullptr, nullptr);

    k_pool<<<256, 256, 0, stream>>>(M, batch, pooled);
    k_head<<<1, 512, 0, stream>>>(pooled, Wout, bout, (float*)d_out);
}

// Round 9
// 381.204 us; speedup vs baseline: 1.9361x; 1.0830x over previous
//
#include <hip/hip_runtime.h>
#include <math.h>
#include <stdint.h>

#define N_NODES 100000
#define N_EDGES 1600000
#define N_GRAPHS 64
#define NPART 8
#define PART_SZ 12500   // N_NODES / NPART

// ---------------- workspace layout (bytes) ----------------
// cnt     @ 0        : 100000 int
// row_ptr @ 400128   : 100001 int
// col     @ 800256   : 1600000 int (6.4 MB)
// pooled  @ 7200384  : 64*64 float
// bsum    @ 7216768  : 128 int
// M       @ 7217408  : 100000*64 fp32 (25.6 MB)  means / final h
//   slot  @ 7217408  : 1600000 int (6.4 MB) ALIASES M (dead before 1st agg)
// Hhi     @ 32817408 : 100000*64 bf16 (12.8 MB)
// Hlo     @ 45617408 : 100000*64 bf16 (12.8 MB)
// total ~58.4 MB

typedef __attribute__((ext_vector_type(8))) short bf16x8;
typedef __attribute__((ext_vector_type(8))) unsigned short u16x8;
typedef __attribute__((ext_vector_type(4))) float f32x4;

__device__ __forceinline__ void atomicMaxFloat(float* addr, float val) {
    if (val >= 0.0f) {
        atomicMax((int*)addr, __float_as_int(val));
    } else {
        atomicMin((unsigned int*)addr, __float_as_uint(val));
    }
}

__device__ __forceinline__ unsigned short f2bf(float f) {   // RNE fp32 -> bf16
    unsigned u = __float_as_uint(f);
    unsigned r = (u + 0x7FFFu + ((u >> 16) & 1u)) >> 16;
    return (unsigned short)r;
}
__device__ __forceinline__ float bf2f(unsigned short b) {
    return __uint_as_float(((unsigned)b) << 16);
}

__global__ void k_init(int* __restrict__ cnt, float* __restrict__ pooled) {
    int i = blockIdx.x * blockDim.x + threadIdx.x;
    if (i < N_NODES) cnt[i] = 0;
    if (i < N_GRAPHS * 64) pooled[i] = -INFINITY;
}

// ---------------------------------------------------------------------------
// ONE atomic pass: slot[e] = old count of dst[e]; final cnt[] = histogram.
// (R8 paid the 1.6M-LLC-atomic tax twice: k_hist AND k_fill. Now once.)
// ---------------------------------------------------------------------------
__global__ void k_slot(const int* __restrict__ dst, int* __restrict__ cnt,
                       int* __restrict__ slot) {
    int e = blockIdx.x * blockDim.x + threadIdx.x;
    if (e < N_EDGES) slot[e] = atomicAdd(&cnt[dst[e]], 1);
}

#define SCAN_CHUNK 1024

__global__ void k_scan1(const int* __restrict__ cnt, int* __restrict__ bsum) {
    __shared__ int lds[256];
    int b = blockIdx.x, t = threadIdx.x;
    int base = b * SCAN_CHUNK + t * 4;
    int s = 0;
#pragma unroll
    for (int j = 0; j < 4; ++j) {
        int i = base + j;
        if (i < N_NODES) s += cnt[i];
    }
    lds[t] = s;
    __syncthreads();
    for (int off = 128; off > 0; off >>= 1) {
        if (t < off) lds[t] += lds[t + off];
        __syncthreads();
    }
    if (t == 0) bsum[b] = lds[0];
}

__global__ void k_scan2(int* __restrict__ bsum, int nb) {
    if (threadIdx.x == 0 && blockIdx.x == 0) {
        int acc = 0;
        for (int i = 0; i < nb; ++i) { int v = bsum[i]; bsum[i] = acc; acc += v; }
    }
}

__global__ void k_scan3(const int* __restrict__ cnt, const int* __restrict__ bsum,
                        int* __restrict__ row_ptr) {
    __shared__ int lds[256];
    int b = blockIdx.x, t = threadIdx.x;
    int base = b * SCAN_CHUNK + t * 4;
    int v[4];
    int s = 0;
#pragma unroll
    for (int j = 0; j < 4; ++j) {
        int i = base + j;
        v[j] = (i < N_NODES) ? cnt[i] : 0;
        s += v[j];
    }
    lds[t] = s;
    __syncthreads();
    for (int off = 1; off < 256; off <<= 1) {
        int add = (t >= off) ? lds[t - off] : 0;
        __syncthreads();
        lds[t] += add;
        __syncthreads();
    }
    int ex = bsum[b] + ((t > 0) ? lds[t - 1] : 0);
#pragma unroll
    for (int j = 0; j < 4; ++j) {
        int i = base + j;
        if (i < N_NODES) { ex += v[j]; row_ptr[i + 1] = ex; }
    }
    if (b == 0 && t == 0) row_ptr[0] = 0;
}

// ---------------------------------------------------------------------------
// Atomic-free XCD-partitioned scatter: col[row_ptr[d] + slot[e]] = src[e].
// blockIdx%8==p (round-robin->XCD heuristic) owns dst range p: col lines for
// a partition are written from ONE L2 -> written back once. dst re-read 8x
// from L2/L3 (cheap).
// ---------------------------------------------------------------------------
__global__ __launch_bounds__(256) void k_scatter_part(
    const int* __restrict__ src, const int* __restrict__ dst,
    const int* __restrict__ row_ptr, const int* __restrict__ slot,
    int* __restrict__ col) {
    int p = blockIdx.x & (NPART - 1);
    int chunk = blockIdx.x >> 3;
    int nchunk = gridDim.x >> 3;
    int lo = p * PART_SZ, hi = lo + PART_SZ;
    for (int e = chunk * 256 + threadIdx.x; e < N_EDGES; e += nchunk * 256) {
        int d = dst[e];
        if (d >= lo && d < hi) {
            col[row_ptr[d] + slot[e]] = src[e];
        }
    }
}

// Convert input x (fp32, stride 32) -> bf16 hi plane (stride 32) for gathers.
__global__ void k_xcast(const float* __restrict__ x, unsigned short* __restrict__ xhi) {
    int i = blockIdx.x * blockDim.x + threadIdx.x;   // one u16x8 per thread
    int base = i * 8;
    if (base >= N_NODES * 32) return;
    const float4* xp = (const float4*)(x + base);
    float4 a = xp[0], b = xp[1];
    u16x8 o;
    o[0] = f2bf(a.x); o[1] = f2bf(a.y); o[2] = f2bf(a.z); o[3] = f2bf(a.w);
    o[4] = f2bf(b.x); o[5] = f2bf(b.y); o[6] = f2bf(b.z); o[7] = f2bf(b.w);
    *(u16x8*)(xhi + base) = o;
}

// ---------------------------------------------------------------------------
// Aggregation from the bf16 HI plane: mean[node][k] (fp32, stride 64).
// ---------------------------------------------------------------------------
#define NC 16

template <int FIN>
__global__ __launch_bounds__(256) void k_agg_bf(
    const unsigned short* __restrict__ hb,   // stride FIN
    const int* __restrict__ row_ptr, const int* __restrict__ col,
    float* __restrict__ mean) {
    int lane = threadIdx.x & 63;
    int wave = blockIdx.x * 4 + (threadIdx.x >> 6);
    int base = wave * NC;
    if (base >= N_NODES) return;
    int rp = row_ptr[base + (lane < NC ? lane : NC)];

    for (int i = 0; i < NC; ++i) {
        int node = base + i;
        int start = __shfl(rp, i);
        int end   = __shfl(rp, i + 1);
        float s = 0.0f;

        if constexpr (FIN == 64) {
            for (int eb = start; eb < end; eb += 64) {
                int n = end - eb; if (n > 64) n = 64;
                int c = (eb + lane < end) ? col[eb + lane] : 0;
                int j = 0;
                for (; j + 7 < n; j += 8) {
                    int c0 = __shfl(c, j),     c1 = __shfl(c, j + 1);
                    int c2 = __shfl(c, j + 2), c3 = __shfl(c, j + 3);
                    int c4 = __shfl(c, j + 4), c5 = __shfl(c, j + 5);
                    int c6 = __shfl(c, j + 6), c7 = __shfl(c, j + 7);
                    float a0 = bf2f(hb[(size_t)c0 * 64 + lane]);
                    float a1 = bf2f(hb[(size_t)c1 * 64 + lane]);
                    float a2 = bf2f(hb[(size_t)c2 * 64 + lane]);
                    float a3 = bf2f(hb[(size_t)c3 * 64 + lane]);
                    float a4 = bf2f(hb[(size_t)c4 * 64 + lane]);
                    float a5 = bf2f(hb[(size_t)c5 * 64 + lane]);
                    float a6 = bf2f(hb[(size_t)c6 * 64 + lane]);
                    float a7 = bf2f(hb[(size_t)c7 * 64 + lane]);
                    s += ((a0 + a1) + (a2 + a3)) + ((a4 + a5) + (a6 + a7));
                }
                for (; j < n; ++j) {
                    int cc = __shfl(c, j);
                    s += bf2f(hb[(size_t)cc * 64 + lane]);
                }
            }
        } else {  // FIN == 32: halves take alternating edges
            int k = lane & 31;
            int half = lane >> 5;
            for (int eb = start; eb < end; eb += 64) {
                int n = end - eb; if (n > 64) n = 64;
                int c = (eb + lane < end) ? col[eb + lane] : 0;
                int j = 0;
                for (; j + 7 < n; j += 8) {
                    int c0 = __shfl(c, j + half);
                    int c1 = __shfl(c, j + 2 + half);
                    int c2 = __shfl(c, j + 4 + half);
                    int c3 = __shfl(c, j + 6 + half);
                    float a0 = bf2f(hb[(size_t)c0 * 32 + k]);
                    float a1 = bf2f(hb[(size_t)c1 * 32 + k]);
                    float a2 = bf2f(hb[(size_t)c2 * 32 + k]);
                    float a3 = bf2f(hb[(size_t)c3 * 32 + k]);
                    s += (a0 + a1) + (a2 + a3);
                }
                for (; j < n; j += 2) {
                    if (j + half < n) {
                        int cc = __shfl(c, j + half);
                        s += bf2f(hb[(size_t)cc * 32 + k]);
                    }
                }
            }
            s += __shfl_xor(s, 32);
        }

        int deg = end - start;
        float m = (deg > 0) ? s / (float)deg : 0.0f;
        if (FIN == 64 || lane < 32) mean[node * 64 + (FIN == 64 ? lane : (lane & 31))] = m;
    }
}

// ---------------------------------------------------------------------------
// Dense transform via MFMA (see R7 notes): out = mean @ Wl + bl + h @ Wr
// ---------------------------------------------------------------------------
template <int KM, bool XBF, int KX, int XS, bool OUTBF>
__global__ __launch_bounds__(256) void k_dense_mfma(
    const float* mean,                        // stride 64, may alias out
    const float* x,                           // fp32 path (XBF=false)
    const unsigned short* xhi, const unsigned short* xlo,  // bf16 path
    const float* __restrict__ Wl, const float* __restrict__ bl,
    const float* __restrict__ Wr,
    float* outf, unsigned short* ohi, unsigned short* olo) {
    int lane = threadIdx.x & 63;
    int strip = blockIdx.x * 4 + (threadIdx.x >> 6);
    if (strip * 16 >= N_NODES) return;
    int row0 = strip * 16;
    int m = lane & 15;
    int g = lane >> 4;

    f32x4 acc[4] = {};

    // ---- mean @ Wl (fp32 -> hi/lo split) ----
#pragma unroll
    for (int kt = 0; kt < KM / 32; ++kt) {
        int k0 = kt * 32 + g * 8;
        const float4* ap = (const float4*)(mean + (size_t)(row0 + m) * 64 + k0);
        float4 a0 = ap[0], a1 = ap[1];
        float av[8] = {a0.x, a0.y, a0.z, a0.w, a1.x, a1.y, a1.z, a1.w};
        bf16x8 ahi, alo;
#pragma unroll
        for (int j = 0; j < 8; ++j) {
            unsigned short hb = f2bf(av[j]);
            ahi[j] = (short)hb;
            alo[j] = (short)f2bf(av[j] - bf2f(hb));
        }
#pragma unroll
        for (int nt = 0; nt < 4; ++nt) {
            bf16x8 b;
#pragma unroll
            for (int j = 0; j < 8; ++j)
                b[j] = (short)f2bf(Wl[(size_t)(k0 + j) * 64 + nt * 16 + m]);
            acc[nt] = __builtin_amdgcn_mfma_f32_16x16x32_bf16(ahi, b, acc[nt], 0, 0, 0);
            acc[nt] = __builtin_amdgcn_mfma_f32_16x16x32_bf16(alo, b, acc[nt], 0, 0, 0);
        }
    }
    // ---- h @ Wr ----
#pragma unroll
    for (int kt = 0; kt < KX / 32; ++kt) {
        int k0 = kt * 32 + g * 8;
        bf16x8 ahi, alo;
        if constexpr (XBF) {
            ahi = *(const bf16x8*)(xhi + (size_t)(row0 + m) * XS + k0);
            alo = *(const bf16x8*)(xlo + (size_t)(row0 + m) * XS + k0);
        } else {
            const float4* ap = (const float4*)(x + (size_t)(row0 + m) * XS + k0);
            float4 a0 = ap[0], a1 = ap[1];
            float av[8] = {a0.x, a0.y, a0.z, a0.w, a1.x, a1.y, a1.z, a1.w};
#pragma unroll
            for (int j = 0; j < 8; ++j) {
                unsigned short hb = f2bf(av[j]);
                ahi[j] = (short)hb;
                alo[j] = (short)f2bf(av[j] - bf2f(hb));
            }
        }
#pragma unroll
        for (int nt = 0; nt < 4; ++nt) {
            bf16x8 b;
#pragma unroll
            for (int j = 0; j < 8; ++j)
                b[j] = (short)f2bf(Wr[(size_t)(k0 + j) * 64 + nt * 16 + m]);
            acc[nt] = __builtin_amdgcn_mfma_f32_16x16x32_bf16(ahi, b, acc[nt], 0, 0, 0);
            acc[nt] = __builtin_amdgcn_mfma_f32_16x16x32_bf16(alo, b, acc[nt], 0, 0, 0);
        }
    }
    // ---- bias + store ----
#pragma unroll
    for (int nt = 0; nt < 4; ++nt) {
        float bias = bl[nt * 16 + m];
#pragma unroll
        for (int r = 0; r < 4; ++r) {
            int row = row0 + g * 4 + r;
            float v = acc[nt][r] + bias;
            if constexpr (OUTBF) {
                unsigned short hb = f2bf(v);
                ohi[(size_t)row * 64 + nt * 16 + m] = hb;
                olo[(size_t)row * 64 + nt * 16 + m] = f2bf(v - bf2f(hb));
            } else {
                outf[(size_t)row * 64 + nt * 16 + m] = v;
            }
        }
    }
}

__global__ __launch_bounds__(256) void k_pool(const float* __restrict__ h,
                                              const int* __restrict__ batch,
                                              float* __restrict__ pooled) {
    int lane = threadIdx.x & 63;
    int wave = (blockIdx.x * blockDim.x + threadIdx.x) >> 6;
    int nWaves = (gridDim.x * blockDim.x) >> 6;
    int per = (N_NODES + nWaves - 1) / nWaves;
    int beg = wave * per;
    int end = beg + per; if (end > N_NODES) end = N_NODES;
    if (beg >= end) return;
    int curg = batch[beg];
    float m = -INFINITY;
    for (int i = beg; i < end; ++i) {
        int g = batch[i];
        if (g != curg) {
            atomicMaxFloat(&pooled[curg * 64 + lane], m);
            m = -INFINITY;
            curg = g;
        }
        m = fmaxf(m, h[(size_t)i * 64 + lane]);
    }
    atomicMaxFloat(&pooled[curg * 64 + lane], m);
}

__global__ void k_head(const float* __restrict__ pooled,
                       const float* __restrict__ Wout,
                       const float* __restrict__ bout, float* __restrict__ out) {
    int tid = threadIdx.x;          // 512 threads: g = tid>>3, o = tid&7
    int g = tid >> 3, o = tid & 7;
    float acc = bout[o];
#pragma unroll
    for (int k = 0; k < 64; ++k) acc += pooled[g * 64 + k] * Wout[k * 8 + o];
    float mx = acc;
#pragma unroll
    for (int m = 1; m < 8; m <<= 1) mx = fmaxf(mx, __shfl_xor(mx, m));
    float ex = expf(acc - mx);
    float sum = ex;
#pragma unroll
    for (int m = 1; m < 8; m <<= 1) sum += __shfl_xor(sum, m);
    out[g * 8 + o] = (acc - mx) - logf(sum);
}

extern "C" void kernel_launch(void* const* d_in, const int* in_sizes, int n_in,
                              void* d_out, int out_size, void* d_ws, size_t ws_size,
                              hipStream_t stream) {
    const float* x    = (const float*)d_in[0];
    const float* Wl0  = (const float*)d_in[1];
    const float* bl0  = (const float*)d_in[2];
    const float* Wr0  = (const float*)d_in[3];
    const float* Wl1  = (const float*)d_in[4];
    const float* bl1  = (const float*)d_in[5];
    const float* Wr1  = (const float*)d_in[6];
    const float* Wl2  = (const float*)d_in[7];
    const float* bl2  = (const float*)d_in[8];
    const float* Wr2  = (const float*)d_in[9];
    const float* Wout = (const float*)d_in[10];
    const float* bout = (const float*)d_in[11];
    const int*   eidx = (const int*)d_in[12];
    const int*   batch= (const int*)d_in[13];
    const int* src = eidx;
    const int* dst = eidx + N_EDGES;

    uint8_t* ws = (uint8_t*)d_ws;
    int*   cnt     = (int*)(ws + 0);
    int*   row_ptr = (int*)(ws + 400128);
    int*   col     = (int*)(ws + 800256);
    float* pooled  = (float*)(ws + 7200384);
    int*   bsum    = (int*)(ws + 7216768);
    float* M       = (float*)(ws + 7217408);
    int*   slot    = (int*)(ws + 7217408);          // aliases M (dead before agg)
    unsigned short* Hhi = (unsigned short*)(ws + 32817408);
    unsigned short* Hlo = (unsigned short*)(ws + 45617408);

    int nb = (N_NODES + SCAN_CHUNK - 1) / SCAN_CHUNK;  // 98

    k_init<<<(N_NODES + 255) / 256, 256, 0, stream>>>(cnt, pooled);
    k_slot<<<(N_EDGES + 255) / 256, 256, 0, stream>>>(dst, cnt, slot);
    k_scan1<<<nb, 256, 0, stream>>>(cnt, bsum);
    k_scan2<<<1, 64, 0, stream>>>(bsum, nb);
    k_scan3<<<nb, 256, 0, stream>>>(cnt, bsum, row_ptr);
    k_scatter_part<<<NPART * 128, 256, 0, stream>>>(src, dst, row_ptr, slot, col);
    k_xcast<<<(N_NODES * 32 / 8 + 255) / 256, 256, 0, stream>>>(x, Hhi);

    int aggBlocks = (N_NODES / NC + 3) / 4;        // 1563
    int mfmaBlocks = (N_NODES / 16 + 3) / 4;       // 1563

    // layer 0: mean0 (from x-hi gathers) -> M; h1 -> Hhi/Hlo (overwrites x-hi)
    k_agg_bf<32><<<aggBlocks, 256, 0, stream>>>(Hhi, row_ptr, col, M);
    k_dense_mfma<32, false, 32, 32, true><<<mfmaBlocks, 256, 0, stream>>>(
        M, x, nullptr, nullptr, Wl0, bl0, Wr0, nullptr, Hhi, Hlo);
    // layer 1: mean1 (from h1-hi gathers) -> M; h2 -> Hhi/Hlo (in-place)
    k_agg_bf<64><<<aggBlocks, 256, 0, stream>>>(Hhi, row_ptr, col, M);
    k_dense_mfma<64, true, 64, 64, true><<<mfmaBlocks, 256, 0, stream>>>(
        M, nullptr, Hhi, Hlo, Wl1, bl1, Wr1, nullptr, Hhi, Hlo);
    // layer 2: mean2 -> M; h3 (fp32) -> M in-place; pool reads M
    k_agg_bf<64><<<aggBlocks, 256, 0, stream>>>(Hhi, row_ptr, col, M);
    k_dense_mfma<64, true, 64, 64, false><<<mfmaBlocks, 256, 0, stream>>>(
        M, nullptr, Hhi, Hlo, Wl2, bl2, Wr2, M, nullptr, nullptr);

    k_pool<<<256, 256, 0, stream>>>(M, batch, pooled);
    k_head<<<1, 512, 0, stream>>>(pooled, Wout, bout, (float*)d_out);
}

// Round 10
// 327.001 us; speedup vs baseline: 2.2570x; 1.1658x over previous
//
#include <hip/hip_runtime.h>
#include <math.h>
#include <stdint.h>

#define N_NODES 100000
#define N_EDGES 1600000
#define N_GRAPHS 64

// ---- atomic-free CSR build geometry ----
#define BSH 9                  // bucket width = 512 nodes
#define NBKT 196               // ceil(100000/512)
#define NCHUNK 256
#define EPC 6250               // N_EDGES / NCHUNK
#define FLAT (NBKT * NCHUNK)   // 50176

// ---------------- workspace layout (bytes) ----------------
// S(histMat)@ 0       : 50177 int (200,708 B; budget 400128)
// row_ptr @ 400128   : 100001 int
// col     @ 800256   : 1600000 int (6.4 MB)
// pooled  @ 7200384  : 64*64 float
// M       @ 7217408  : 100000*64 fp32 (25.6 MB)  means / final h
//   pairs @ 7217408  : 1600000 int2 (12.8 MB) ALIASES M (dead before 1st agg)
// Hhi     @ 32817408 : 100000*64 bf16 (12.8 MB)
// Hlo     @ 45617408 : 100000*64 bf16 (12.8 MB)
// total ~58.4 MB

typedef __attribute__((ext_vector_type(8))) short bf16x8;
typedef __attribute__((ext_vector_type(8))) unsigned short u16x8;
typedef __attribute__((ext_vector_type(4))) float f32x4;

__device__ __forceinline__ void atomicMaxFloat(float* addr, float val) {
    if (val >= 0.0f) {
        atomicMax((int*)addr, __float_as_int(val));
    } else {
        atomicMin((unsigned int*)addr, __float_as_uint(val));
    }
}

__device__ __forceinline__ unsigned short f2bf(float f) {   // RNE fp32 -> bf16
    unsigned u = __float_as_uint(f);
    unsigned r = (u + 0x7FFFu + ((u >> 16) & 1u)) >> 16;
    return (unsigned short)r;
}
__device__ __forceinline__ float bf2f(unsigned short b) {
    return __uint_as_float(((unsigned)b) << 16);
}

__global__ void k_init(float* __restrict__ pooled) {
    int i = blockIdx.x * blockDim.x + threadIdx.x;
    if (i < N_GRAPHS * 64) pooled[i] = -INFINITY;
}

// ---- CSR phase 1: per-chunk coarse-bucket histogram (LDS atomics only) ----
__global__ __launch_bounds__(256) void k_rhist(const int* __restrict__ dst,
                                               int* __restrict__ S) {
    __shared__ int h[NBKT];
    for (int i = threadIdx.x; i < NBKT; i += 256) h[i] = 0;
    __syncthreads();
    int c = blockIdx.x;
    int e0 = c * EPC;
    for (int e = e0 + threadIdx.x; e < e0 + EPC; e += 256)
        atomicAdd(&h[dst[e] >> BSH], 1);
    __syncthreads();
    for (int i = threadIdx.x; i < NBKT; i += 256) S[i * NCHUNK + c] = h[i];
}

// ---- CSR phase 2: exclusive scan of S[0..FLAT) in place; S[FLAT]=total ----
__global__ __launch_bounds__(1024) void k_rscan(int* __restrict__ S) {
    __shared__ int part[1024];
    int t = threadIdx.x;
    const int seg = (FLAT + 1023) / 1024;   // 49
    int lo = t * seg;
    int hi = lo + seg; if (hi > FLAT) hi = FLAT;
    int s = 0;
    for (int i = lo; i < hi; ++i) s += S[i];
    part[t] = s;
    __syncthreads();
    for (int off = 1; off < 1024; off <<= 1) {
        int add = (t >= off) ? part[t - off] : 0;
        __syncthreads();
        part[t] += add;
        __syncthreads();
    }
    int ex = (t > 0) ? part[t - 1] : 0;
    if (t == 1023) S[FLAT] = part[1023];
    int run = ex;
    for (int i = lo; i < hi; ++i) { int v = S[i]; S[i] = run; run += v; }
}

// ---- CSR phase 3: scatter (src,dst) pairs bucket-grouped, no global atomics ----
__global__ __launch_bounds__(256) void k_rscatter(
    const int* __restrict__ src, const int* __restrict__ dst,
    const int* __restrict__ S, int2* __restrict__ pairs) {
    __shared__ int ofs[NBKT];
    __shared__ int cnt[NBKT];
    int c = blockIdx.x;
    for (int i = threadIdx.x; i < NBKT; i += 256) {
        ofs[i] = S[i * NCHUNK + c];
        cnt[i] = 0;
    }
    __syncthreads();
    int e0 = c * EPC;
    for (int e = e0 + threadIdx.x; e < e0 + EPC; e += 256) {
        int d = dst[e];
        int b = d >> BSH;
        int r = atomicAdd(&cnt[b], 1);           // LDS atomic
        pairs[ofs[b] + r] = make_int2(src[e], d);
    }
}

// ---- CSR phase 4: per bucket, build row_ptr + col (all LDS-local) ----
__global__ __launch_bounds__(256) void k_rbuild(
    const int2* __restrict__ pairs, const int* __restrict__ S,
    int* __restrict__ row_ptr, int* __restrict__ col) {
    __shared__ int ncnt[512];
    __shared__ int nofs[512];
    __shared__ int part[256];
    int b = blockIdx.x;
    int t = threadIdx.x;
    int base = S[b * NCHUNK];
    int next = (b == NBKT - 1) ? S[FLAT] : S[(b + 1) * NCHUNK];
    int count = next - base;
    int nodeBase = b << BSH;

    ncnt[2 * t] = 0; ncnt[2 * t + 1] = 0;
    __syncthreads();
    for (int i = t; i < count; i += 256)
        atomicAdd(&ncnt[pairs[base + i].y - nodeBase], 1);
    __syncthreads();
    // exclusive scan of ncnt[512]
    int v0 = ncnt[2 * t], v1 = ncnt[2 * t + 1];
    part[t] = v0 + v1;
    __syncthreads();
    for (int off = 1; off < 256; off <<= 1) {
        int add = (t >= off) ? part[t - off] : 0;
        __syncthreads();
        part[t] += add;
        __syncthreads();
    }
    int ex = (t > 0) ? part[t - 1] : 0;
    nofs[2 * t] = ex;
    nofs[2 * t + 1] = ex + v0;
    ncnt[2 * t] = 0; ncnt[2 * t + 1] = 0;
    __syncthreads();
    // row_ptr
    for (int i = t; i < 512; i += 256) {
        int node = nodeBase + i;
        if (node < N_NODES) row_ptr[node] = base + nofs[i];
    }
    if (b == 0 && t == 0) row_ptr[N_NODES] = N_EDGES;
    // col scatter (rank via LDS atomic; order within node irrelevant)
    for (int i = t; i < count; i += 256) {
        int2 p = pairs[base + i];
        int li = p.y - nodeBase;
        int r = atomicAdd(&ncnt[li], 1);
        col[base + nofs[li] + r] = p.x;
    }
}

// Convert input x (fp32, stride 32) -> bf16 hi plane (stride 32) for gathers.
__global__ void k_xcast(const float* __restrict__ x, unsigned short* __restrict__ xhi) {
    int i = blockIdx.x * blockDim.x + threadIdx.x;   // one u16x8 per thread
    int base = i * 8;
    if (base >= N_NODES * 32) return;
    const float4* xp = (const float4*)(x + base);
    float4 a = xp[0], b = xp[1];
    u16x8 o;
    o[0] = f2bf(a.x); o[1] = f2bf(a.y); o[2] = f2bf(a.z); o[3] = f2bf(a.w);
    o[4] = f2bf(b.x); o[5] = f2bf(b.y); o[6] = f2bf(b.z); o[7] = f2bf(b.w);
    *(u16x8*)(xhi + base) = o;
}

// ---------------------------------------------------------------------------
// Aggregation from the bf16 HI plane: mean[node][k] (fp32, stride 64).
// ---------------------------------------------------------------------------
#define NC 16

template <int FIN>
__global__ __launch_bounds__(256) void k_agg_bf(
    const unsigned short* __restrict__ hb,   // stride FIN
    const int* __restrict__ row_ptr, const int* __restrict__ col,
    float* __restrict__ mean) {
    int lane = threadIdx.x & 63;
    int wave = blockIdx.x * 4 + (threadIdx.x >> 6);
    int base = wave * NC;
    if (base >= N_NODES) return;
    int rp = row_ptr[base + (lane < NC ? lane : NC)];

    for (int i = 0; i < NC; ++i) {
        int node = base + i;
        int start = __shfl(rp, i);
        int end   = __shfl(rp, i + 1);
        float s = 0.0f;

        if constexpr (FIN == 64) {
            for (int eb = start; eb < end; eb += 64) {
                int n = end - eb; if (n > 64) n = 64;
                int c = (eb + lane < end) ? col[eb + lane] : 0;
                int j = 0;
                for (; j + 7 < n; j += 8) {
                    int c0 = __shfl(c, j),     c1 = __shfl(c, j + 1);
                    int c2 = __shfl(c, j + 2), c3 = __shfl(c, j + 3);
                    int c4 = __shfl(c, j + 4), c5 = __shfl(c, j + 5);
                    int c6 = __shfl(c, j + 6), c7 = __shfl(c, j + 7);
                    float a0 = bf2f(hb[(size_t)c0 * 64 + lane]);
                    float a1 = bf2f(hb[(size_t)c1 * 64 + lane]);
                    float a2 = bf2f(hb[(size_t)c2 * 64 + lane]);
                    float a3 = bf2f(hb[(size_t)c3 * 64 + lane]);
                    float a4 = bf2f(hb[(size_t)c4 * 64 + lane]);
                    float a5 = bf2f(hb[(size_t)c5 * 64 + lane]);
                    float a6 = bf2f(hb[(size_t)c6 * 64 + lane]);
                    float a7 = bf2f(hb[(size_t)c7 * 64 + lane]);
                    s += ((a0 + a1) + (a2 + a3)) + ((a4 + a5) + (a6 + a7));
                }
                for (; j < n; ++j) {
                    int cc = __shfl(c, j);
                    s += bf2f(hb[(size_t)cc * 64 + lane]);
                }
            }
        } else {  // FIN == 32: halves take alternating edges
            int k = lane & 31;
            int half = lane >> 5;
            for (int eb = start; eb < end; eb += 64) {
                int n = end - eb; if (n > 64) n = 64;
                int c = (eb + lane < end) ? col[eb + lane] : 0;
                int j = 0;
                for (; j + 7 < n; j += 8) {
                    int c0 = __shfl(c, j + half);
                    int c1 = __shfl(c, j + 2 + half);
                    int c2 = __shfl(c, j + 4 + half);
                    int c3 = __shfl(c, j + 6 + half);
                    float a0 = bf2f(hb[(size_t)c0 * 32 + k]);
                    float a1 = bf2f(hb[(size_t)c1 * 32 + k]);
                    float a2 = bf2f(hb[(size_t)c2 * 32 + k]);
                    float a3 = bf2f(hb[(size_t)c3 * 32 + k]);
                    s += (a0 + a1) + (a2 + a3);
                }
                for (; j < n; j += 2) {
                    if (j + half < n) {
                        int cc = __shfl(c, j + half);
                        s += bf2f(hb[(size_t)cc * 32 + k]);
                    }
                }
            }
            s += __shfl_xor(s, 32);
        }

        int deg = end - start;
        float m = (deg > 0) ? s / (float)deg : 0.0f;
        if (FIN == 64 || lane < 32) mean[node * 64 + (FIN == 64 ? lane : (lane & 31))] = m;
    }
}

// ---------------------------------------------------------------------------
// Dense transform via MFMA: out = mean @ Wl + bl + h @ Wr (hi/lo bf16 split)
// ---------------------------------------------------------------------------
template <int KM, bool XBF, int KX, int XS, bool OUTBF>
__global__ __launch_bounds__(256) void k_dense_mfma(
    const float* mean,                        // stride 64, may alias out
    const float* x,                           // fp32 path (XBF=false)
    const unsigned short* xhi, const unsigned short* xlo,  // bf16 path
    const float* __restrict__ Wl, const float* __restrict__ bl,
    const float* __restrict__ Wr,
    float* outf, unsigned short* ohi, unsigned short* olo) {
    int lane = threadIdx.x & 63;
    int strip = blockIdx.x * 4 + (threadIdx.x >> 6);
    if (strip * 16 >= N_NODES) return;
    int row0 = strip * 16;
    int m = lane & 15;
    int g = lane >> 4;

    f32x4 acc[4] = {};

    // ---- mean @ Wl (fp32 -> hi/lo split) ----
#pragma unroll
    for (int kt = 0; kt < KM / 32; ++kt) {
        int k0 = kt * 32 + g * 8;
        const float4* ap = (const float4*)(mean + (size_t)(row0 + m) * 64 + k0);
        float4 a0 = ap[0], a1 = ap[1];
        float av[8] = {a0.x, a0.y, a0.z, a0.w, a1.x, a1.y, a1.z, a1.w};
        bf16x8 ahi, alo;
#pragma unroll
        for (int j = 0; j < 8; ++j) {
            unsigned short hb = f2bf(av[j]);
            ahi[j] = (short)hb;
            alo[j] = (short)f2bf(av[j] - bf2f(hb));
        }
#pragma unroll
        for (int nt = 0; nt < 4; ++nt) {
            bf16x8 b;
#pragma unroll
            for (int j = 0; j < 8; ++j)
                b[j] = (short)f2bf(Wl[(size_t)(k0 + j) * 64 + nt * 16 + m]);
            acc[nt] = __builtin_amdgcn_mfma_f32_16x16x32_bf16(ahi, b, acc[nt], 0, 0, 0);
            acc[nt] = __builtin_amdgcn_mfma_f32_16x16x32_bf16(alo, b, acc[nt], 0, 0, 0);
        }
    }
    // ---- h @ Wr ----
#pragma unroll
    for (int kt = 0; kt < KX / 32; ++kt) {
        int k0 = kt * 32 + g * 8;
        bf16x8 ahi, alo;
        if constexpr (XBF) {
            ahi = *(const bf16x8*)(xhi + (size_t)(row0 + m) * XS + k0);
            alo = *(const bf16x8*)(xlo + (size_t)(row0 + m) * XS + k0);
        } else {
            const float4* ap = (const float4*)(x + (size_t)(row0 + m) * XS + k0);
            float4 a0 = ap[0], a1 = ap[1];
            float av[8] = {a0.x, a0.y, a0.z, a0.w, a1.x, a1.y, a1.z, a1.w};
#pragma unroll
            for (int j = 0; j < 8; ++j) {
                unsigned short hb = f2bf(av[j]);
                ahi[j] = (short)hb;
                alo[j] = (short)f2bf(av[j] - bf2f(hb));
            }
        }
#pragma unroll
        for (int nt = 0; nt < 4; ++nt) {
            bf16x8 b;
#pragma unroll
            for (int j = 0; j < 8; ++j)
                b[j] = (short)f2bf(Wr[(size_t)(k0 + j) * 64 + nt * 16 + m]);
            acc[nt] = __builtin_amdgcn_mfma_f32_16x16x32_bf16(ahi, b, acc[nt], 0, 0, 0);
            acc[nt] = __builtin_amdgcn_mfma_f32_16x16x32_bf16(alo, b, acc[nt], 0, 0, 0);
        }
    }
    // ---- bias + store ----
#pragma unroll
    for (int nt = 0; nt < 4; ++nt) {
        float bias = bl[nt * 16 + m];
#pragma unroll
        for (int r = 0; r < 4; ++r) {
            int row = row0 + g * 4 + r;
            float v = acc[nt][r] + bias;
            if constexpr (OUTBF) {
                unsigned short hb = f2bf(v);
                ohi[(size_t)row * 64 + nt * 16 + m] = hb;
                olo[(size_t)row * 64 + nt * 16 + m] = f2bf(v - bf2f(hb));
            } else {
                outf[(size_t)row * 64 + nt * 16 + m] = v;
            }
        }
    }
}

__global__ __launch_bounds__(256) void k_pool(const float* __restrict__ h,
                                              const int* __restrict__ batch,
                                              float* __restrict__ pooled) {
    int lane = threadIdx.x & 63;
    int wave = (blockIdx.x * blockDim.x + threadIdx.x) >> 6;
    int nWaves = (gridDim.x * blockDim.x) >> 6;
    int per = (N_NODES + nWaves - 1) / nWaves;
    int beg = wave * per;
    int end = beg + per; if (end > N_NODES) end = N_NODES;
    if (beg >= end) return;
    int curg = batch[beg];
    float m = -INFINITY;
    for (int i = beg; i < end; ++i) {
        int g = batch[i];
        if (g != curg) {
            atomicMaxFloat(&pooled[curg * 64 + lane], m);
            m = -INFINITY;
            curg = g;
        }
        m = fmaxf(m, h[(size_t)i * 64 + lane]);
    }
    atomicMaxFloat(&pooled[curg * 64 + lane], m);
}

__global__ void k_head(const float* __restrict__ pooled,
                       const float* __restrict__ Wout,
                       const float* __restrict__ bout, float* __restrict__ out) {
    int tid = threadIdx.x;          // 512 threads: g = tid>>3, o = tid&7
    int g = tid >> 3, o = tid & 7;
    float acc = bout[o];
#pragma unroll
    for (int k = 0; k < 64; ++k) acc += pooled[g * 64 + k] * Wout[k * 8 + o];
    float mx = acc;
#pragma unroll
    for (int m = 1; m < 8; m <<= 1) mx = fmaxf(mx, __shfl_xor(mx, m));
    float ex = expf(acc - mx);
    float sum = ex;
#pragma unroll
    for (int m = 1; m < 8; m <<= 1) sum += __shfl_xor(sum, m);
    out[g * 8 + o] = (acc - mx) - logf(sum);
}

extern "C" void kernel_launch(void* const* d_in, const int* in_sizes, int n_in,
                              void* d_out, int out_size, void* d_ws, size_t ws_size,
                              hipStream_t stream) {
    const float* x    = (const float*)d_in[0];
    const float* Wl0  = (const float*)d_in[1];
    const float* bl0  = (const float*)d_in[2];
    const float* Wr0  = (const float*)d_in[3];
    const float* Wl1  = (const float*)d_in[4];
    const float* bl1  = (const float*)d_in[5];
    const float* Wr1  = (const float*)d_in[6];
    const float* Wl2  = (const float*)d_in[7];
    const float* bl2  = (const float*)d_in[8];
    const float* Wr2  = (const float*)d_in[9];
    const float* Wout = (const float*)d_in[10];
    const float* bout = (const float*)d_in[11];
    const int*   eidx = (const int*)d_in[12];
    const int*   batch= (const int*)d_in[13];
    const int* src = eidx;
    const int* dst = eidx + N_EDGES;

    uint8_t* ws = (uint8_t*)d_ws;
    int*   S       = (int*)(ws + 0);                // 50177 ints
    int*   row_ptr = (int*)(ws + 400128);
    int*   col     = (int*)(ws + 800256);
    float* pooled  = (float*)(ws + 7200384);
    float* M       = (float*)(ws + 7217408);
    int2*  pairs   = (int2*)(ws + 7217408);         // aliases M (dead before agg)
    unsigned short* Hhi = (unsigned short*)(ws + 32817408);
    unsigned short* Hlo = (unsigned short*)(ws + 45617408);

    k_init<<<16, 256, 0, stream>>>(pooled);
    k_rhist<<<NCHUNK, 256, 0, stream>>>(dst, S);
    k_rscan<<<1, 1024, 0, stream>>>(S);
    k_rscatter<<<NCHUNK, 256, 0, stream>>>(src, dst, S, pairs);
    k_rbuild<<<NBKT, 256, 0, stream>>>(pairs, S, row_ptr, col);
    k_xcast<<<(N_NODES * 32 / 8 + 255) / 256, 256, 0, stream>>>(x, Hhi);

    int aggBlocks = (N_NODES / NC + 3) / 4;        // 1563
    int mfmaBlocks = (N_NODES / 16 + 3) / 4;       // 1563

    // layer 0: mean0 (from x-hi gathers) -> M; h1 -> Hhi/Hlo (overwrites x-hi)
    k_agg_bf<32><<<aggBlocks, 256, 0, stream>>>(Hhi, row_ptr, col, M);
    k_dense_mfma<32, false, 32, 32, true><<<mfmaBlocks, 256, 0, stream>>>(
        M, x, nullptr, nullptr, Wl0, bl0, Wr0, nullptr, Hhi, Hlo);
    // layer 1: mean1 (from h1-hi gathers) -> M; h2 -> Hhi/Hlo (in-place)
    k_agg_bf<64><<<aggBlocks, 256, 0, stream>>>(Hhi, row_ptr, col, M);
    k_dense_mfma<64, true, 64, 64, true><<<mfmaBlocks, 256, 0, stream>>>(
        M, nullptr, Hhi, Hlo, Wl1, bl1, Wr1, nullptr, Hhi, Hlo);
    // layer 2: mean2 -> M; h3 (fp32) -> M in-place; pool reads M
    k_agg_bf<64><<<aggBlocks, 256, 0, stream>>>(Hhi, row_ptr, col, M);
    k_dense_mfma<64, true, 64, 64, false><<<mfmaBlocks, 256, 0, stream>>>(
        M, nullptr, Hhi, Hlo, Wl2, bl2, Wr2, M, nullptr, nullptr);

    k_pool<<<256, 256, 0, stream>>>(M, batch, pooled);
    k_head<<<1, 512, 0, stream>>>(pooled, Wout, bout, (float*)d_out);
}

// Round 11
// 285.956 us; speedup vs baseline: 2.5810x; 1.1435x over previous
//
#include <hip/hip_runtime.h>
#include <math.h>
#include <stdint.h>

#define N_NODES 100000
#define N_EDGES 1600000
#define N_GRAPHS 64

// ---- atomic-free CSR build geometry ----
#define BSH 9                  // bucket width = 512 nodes
#define NBKT 196               // ceil(100000/512)
#define NCHUNK 256
#define EPC 6250               // N_EDGES / NCHUNK
#define FLAT (NBKT * NCHUNK)   // 50176

// ---------------- workspace layout (bytes) ----------------
// S(histMat)@ 0      : 50177 int
// row_ptr @ 400128   : 100001 int
// col     @ 800256   : 1600000 int (6.4 MB)
// pooled  @ 7200384  : 64*64 float
// M       @ 7217408  : 100000*64 fp32 (25.6 MB)  means / final h
//   pairs @ 7217408  : 1600000 int2 (12.8 MB) ALIASES M (dead before 1st agg)
// Hhi     @ 32817408 : 100000*64 bf16 (12.8 MB)
// Hlo     @ 45617408 : 100000*64 bf16 (12.8 MB)
// total ~58.4 MB

typedef __attribute__((ext_vector_type(8))) short bf16x8;
typedef __attribute__((ext_vector_type(8))) unsigned short u16x8;
typedef __attribute__((ext_vector_type(4))) float f32x4;

__device__ __forceinline__ void atomicMaxFloat(float* addr, float val) {
    if (val >= 0.0f) {
        atomicMax((int*)addr, __float_as_int(val));
    } else {
        atomicMin((unsigned int*)addr, __float_as_uint(val));
    }
}

__device__ __forceinline__ unsigned short f2bf(float f) {   // RNE fp32 -> bf16
    unsigned u = __float_as_uint(f);
    unsigned r = (u + 0x7FFFu + ((u >> 16) & 1u)) >> 16;
    return (unsigned short)r;
}
__device__ __forceinline__ float bf2f(unsigned short b) {
    return __uint_as_float(((unsigned)b) << 16);
}

__global__ void k_init(float* __restrict__ pooled) {
    int i = blockIdx.x * blockDim.x + threadIdx.x;
    if (i < N_GRAPHS * 64) pooled[i] = -INFINITY;
}

// ---- CSR phase 1: per-chunk coarse-bucket histogram (LDS atomics only) ----
__global__ __launch_bounds__(256) void k_rhist(const int* __restrict__ dst,
                                               int* __restrict__ S) {
    __shared__ int h[NBKT];
    for (int i = threadIdx.x; i < NBKT; i += 256) h[i] = 0;
    __syncthreads();
    int c = blockIdx.x;
    int e0 = c * EPC;
    for (int e = e0 + threadIdx.x; e < e0 + EPC; e += 256)
        atomicAdd(&h[dst[e] >> BSH], 1);
    __syncthreads();
    for (int i = threadIdx.x; i < NBKT; i += 256) S[i * NCHUNK + c] = h[i];
}

// ---- CSR phase 2: exclusive scan of S[0..FLAT) in place; S[FLAT]=total ----
__global__ __launch_bounds__(1024) void k_rscan(int* __restrict__ S) {
    __shared__ int part[1024];
    int t = threadIdx.x;
    const int seg = (FLAT + 1023) / 1024;   // 49
    int lo = t * seg;
    int hi = lo + seg; if (hi > FLAT) hi = FLAT;
    int s = 0;
    for (int i = lo; i < hi; ++i) s += S[i];
    part[t] = s;
    __syncthreads();
    for (int off = 1; off < 1024; off <<= 1) {
        int add = (t >= off) ? part[t - off] : 0;
        __syncthreads();
        part[t] += add;
        __syncthreads();
    }
    int ex = (t > 0) ? part[t - 1] : 0;
    if (t == 1023) S[FLAT] = part[1023];
    int run = ex;
    for (int i = lo; i < hi; ++i) { int v = S[i]; S[i] = run; run += v; }
}

// ---- CSR phase 3: scatter (src,dst) pairs bucket-grouped, no global atomics ----
__global__ __launch_bounds__(256) void k_rscatter(
    const int* __restrict__ src, const int* __restrict__ dst,
    const int* __restrict__ S, int2* __restrict__ pairs) {
    __shared__ int ofs[NBKT];
    __shared__ int cnt[NBKT];
    int c = blockIdx.x;
    for (int i = threadIdx.x; i < NBKT; i += 256) {
        ofs[i] = S[i * NCHUNK + c];
        cnt[i] = 0;
    }
    __syncthreads();
    int e0 = c * EPC;
    for (int e = e0 + threadIdx.x; e < e0 + EPC; e += 256) {
        int d = dst[e];
        int b = d >> BSH;
        int r = atomicAdd(&cnt[b], 1);           // LDS atomic
        pairs[ofs[b] + r] = make_int2(src[e], d);
    }
}

// ---- CSR phase 4: per bucket, build row_ptr + col (all LDS-local) ----
__global__ __launch_bounds__(256) void k_rbuild(
    const int2* __restrict__ pairs, const int* __restrict__ S,
    int* __restrict__ row_ptr, int* __restrict__ col) {
    __shared__ int ncnt[512];
    __shared__ int nofs[512];
    __shared__ int part[256];
    int b = blockIdx.x;
    int t = threadIdx.x;
    int base = S[b * NCHUNK];
    int next = (b == NBKT - 1) ? S[FLAT] : S[(b + 1) * NCHUNK];
    int count = next - base;
    int nodeBase = b << BSH;

    ncnt[2 * t] = 0; ncnt[2 * t + 1] = 0;
    __syncthreads();
    for (int i = t; i < count; i += 256)
        atomicAdd(&ncnt[pairs[base + i].y - nodeBase], 1);
    __syncthreads();
    // exclusive scan of ncnt[512]
    int v0 = ncnt[2 * t], v1 = ncnt[2 * t + 1];
    part[t] = v0 + v1;
    __syncthreads();
    for (int off = 1; off < 256; off <<= 1) {
        int add = (t >= off) ? part[t - off] : 0;
        __syncthreads();
        part[t] += add;
        __syncthreads();
    }
    int ex = (t > 0) ? part[t - 1] : 0;
    nofs[2 * t] = ex;
    nofs[2 * t + 1] = ex + v0;
    ncnt[2 * t] = 0; ncnt[2 * t + 1] = 0;
    __syncthreads();
    // row_ptr
    for (int i = t; i < 512; i += 256) {
        int node = nodeBase + i;
        if (node < N_NODES) row_ptr[node] = base + nofs[i];
    }
    if (b == 0 && t == 0) row_ptr[N_NODES] = N_EDGES;
    // col scatter (rank via LDS atomic; order within node irrelevant)
    for (int i = t; i < count; i += 256) {
        int2 p = pairs[base + i];
        int li = p.y - nodeBase;
        int r = atomicAdd(&ncnt[li], 1);
        col[base + nofs[li] + r] = p.x;
    }
}

// Convert input x (fp32, stride 32) -> bf16 hi plane (stride 32) for gathers.
__global__ void k_xcast(const float* __restrict__ x, unsigned short* __restrict__ xhi) {
    int i = blockIdx.x * blockDim.x + threadIdx.x;   // one u16x8 per thread
    int base = i * 8;
    if (base >= N_NODES * 32) return;
    const float4* xp = (const float4*)(x + base);
    float4 a = xp[0], b = xp[1];
    u16x8 o;
    o[0] = f2bf(a.x); o[1] = f2bf(a.y); o[2] = f2bf(a.z); o[3] = f2bf(a.w);
    o[4] = f2bf(b.x); o[5] = f2bf(b.y); o[6] = f2bf(b.z); o[7] = f2bf(b.w);
    *(u16x8*)(xhi + base) = o;
}

// ---------------------------------------------------------------------------
// Quad-gather aggregation (R10: agg was VMEM-ISSUE bound — one 128B load
// instruction per neighbor row). Now one load instruction fetches G neighbor
// rows: lane group g = lane/(64/G) handles neighbor j+g; each lane loads
// ushort4 (4 features). FIN=64: G=4 (4 rows/instr); FIN=32: G=8.
// VMEM instrs and col-bpermutes drop by G. Cross-group sum: log2(G)+... via
// shfl_xor at node end. mean written as float4 by the first 64/G/... lanes.
// ---------------------------------------------------------------------------
#define NC 16

template <int FIN>
__global__ __launch_bounds__(256) void k_agg_bf(
    const unsigned short* __restrict__ hb,   // stride FIN
    const int* __restrict__ row_ptr, const int* __restrict__ col,
    float* __restrict__ mean) {
    int lane = threadIdx.x & 63;
    int wave = blockIdx.x * 4 + (threadIdx.x >> 6);
    int base = wave * NC;
    if (base >= N_NODES) return;
    int rp = row_ptr[base + (lane < NC ? lane : NC)];

    constexpr int G = (FIN == 64) ? 4 : 8;     // neighbor rows per load instr
    constexpr int LPR = 64 / G;                // lanes per row (16 or 8)
    int g  = lane / LPR;                       // neighbor sub-index
    int fq = lane % LPR;                       // feature quad index

    for (int i = 0; i < NC; ++i) {
        int node = base + i;
        int start = __shfl(rp, i);
        int end   = __shfl(rp, i + 1);
        float s0 = 0.0f, s1 = 0.0f, s2 = 0.0f, s3 = 0.0f;

        for (int eb = start; eb < end; eb += 64) {
            int n = end - eb; if (n > 64) n = 64;
            int c = (eb + lane < end) ? col[eb + lane] : 0;
            int j = 0;
            for (; j + 2 * G - 1 < n; j += 2 * G) {        // 2 quads in flight
                int cA = __shfl(c, j + g);
                int cB = __shfl(c, j + G + g);
                ushort4 vA = *(const ushort4*)(hb + (size_t)cA * FIN + fq * 4);
                ushort4 vB = *(const ushort4*)(hb + (size_t)cB * FIN + fq * 4);
                s0 += bf2f(vA.x) + bf2f(vB.x);
                s1 += bf2f(vA.y) + bf2f(vB.y);
                s2 += bf2f(vA.z) + bf2f(vB.z);
                s3 += bf2f(vA.w) + bf2f(vB.w);
            }
            for (; j + G - 1 < n; j += G) {
                int cA = __shfl(c, j + g);
                ushort4 vA = *(const ushort4*)(hb + (size_t)cA * FIN + fq * 4);
                s0 += bf2f(vA.x);
                s1 += bf2f(vA.y);
                s2 += bf2f(vA.z);
                s3 += bf2f(vA.w);
            }
            if (j < n) {                                    // masked tail
                int idx = j + g;
                bool valid = idx < n;
                int cA = __shfl(c, valid ? idx : 0);
                ushort4 vA = *(const ushort4*)(hb + (size_t)cA * FIN + fq * 4);
                if (valid) {
                    s0 += bf2f(vA.x);
                    s1 += bf2f(vA.y);
                    s2 += bf2f(vA.z);
                    s3 += bf2f(vA.w);
                }
            }
        }
        // cross-group reduction: sum over the G neighbor sub-groups
#pragma unroll
        for (int m = LPR; m < 64; m <<= 1) {
            s0 += __shfl_xor(s0, m);
            s1 += __shfl_xor(s1, m);
            s2 += __shfl_xor(s2, m);
            s3 += __shfl_xor(s3, m);
        }
        int deg = end - start;
        float inv = (deg > 0) ? 1.0f / (float)deg : 0.0f;
        if (lane < LPR) {
            *(float4*)(mean + (size_t)node * 64 + fq * 4) =
                make_float4(s0 * inv, s1 * inv, s2 * inv, s3 * inv);
        }
    }
}

// ---------------------------------------------------------------------------
// Dense transform via MFMA: out = mean @ Wl + bl + h @ Wr (hi/lo bf16 split)
// ---------------------------------------------------------------------------
template <int KM, bool XBF, int KX, int XS, bool OUTBF>
__global__ __launch_bounds__(256) void k_dense_mfma(
    const float* mean,                        // stride 64, may alias out
    const float* x,                           // fp32 path (XBF=false)
    const unsigned short* xhi, const unsigned short* xlo,  // bf16 path
    const float* __restrict__ Wl, const float* __restrict__ bl,
    const float* __restrict__ Wr,
    float* outf, unsigned short* ohi, unsigned short* olo) {
    int lane = threadIdx.x & 63;
    int strip = blockIdx.x * 4 + (threadIdx.x >> 6);
    if (strip * 16 >= N_NODES) return;
    int row0 = strip * 16;
    int m = lane & 15;
    int g = lane >> 4;

    f32x4 acc[4] = {};

    // ---- mean @ Wl (fp32 -> hi/lo split) ----
#pragma unroll
    for (int kt = 0; kt < KM / 32; ++kt) {
        int k0 = kt * 32 + g * 8;
        const float4* ap = (const float4*)(mean + (size_t)(row0 + m) * 64 + k0);
        float4 a0 = ap[0], a1 = ap[1];
        float av[8] = {a0.x, a0.y, a0.z, a0.w, a1.x, a1.y, a1.z, a1.w};
        bf16x8 ahi, alo;
#pragma unroll
        for (int j = 0; j < 8; ++j) {
            unsigned short hb = f2bf(av[j]);
            ahi[j] = (short)hb;
            alo[j] = (short)f2bf(av[j] - bf2f(hb));
        }
#pragma unroll
        for (int nt = 0; nt < 4; ++nt) {
            bf16x8 b;
#pragma unroll
            for (int j = 0; j < 8; ++j)
                b[j] = (short)f2bf(Wl[(size_t)(k0 + j) * 64 + nt * 16 + m]);
            acc[nt] = __builtin_amdgcn_mfma_f32_16x16x32_bf16(ahi, b, acc[nt], 0, 0, 0);
            acc[nt] = __builtin_amdgcn_mfma_f32_16x16x32_bf16(alo, b, acc[nt], 0, 0, 0);
        }
    }
    // ---- h @ Wr ----
#pragma unroll
    for (int kt = 0; kt < KX / 32; ++kt) {
        int k0 = kt * 32 + g * 8;
        bf16x8 ahi, alo;
        if constexpr (XBF) {
            ahi = *(const bf16x8*)(xhi + (size_t)(row0 + m) * XS + k0);
            alo = *(const bf16x8*)(xlo + (size_t)(row0 + m) * XS + k0);
        } else {
            const float4* ap = (const float4*)(x + (size_t)(row0 + m) * XS + k0);
            float4 a0 = ap[0], a1 = ap[1];
            float av[8] = {a0.x, a0.y, a0.z, a0.w, a1.x, a1.y, a1.z, a1.w};
#pragma unroll
            for (int j = 0; j < 8; ++j) {
                unsigned short hb = f2bf(av[j]);
                ahi[j] = (short)hb;
                alo[j] = (short)f2bf(av[j] - bf2f(hb));
            }
        }
#pragma unroll
        for (int nt = 0; nt < 4; ++nt) {
            bf16x8 b;
#pragma unroll
            for (int j = 0; j < 8; ++j)
                b[j] = (short)f2bf(Wr[(size_t)(k0 + j) * 64 + nt * 16 + m]);
            acc[nt] = __builtin_amdgcn_mfma_f32_16x16x32_bf16(ahi, b, acc[nt], 0, 0, 0);
            acc[nt] = __builtin_amdgcn_mfma_f32_16x16x32_bf16(alo, b, acc[nt], 0, 0, 0);
        }
    }
    // ---- bias + store ----
#pragma unroll
    for (int nt = 0; nt < 4; ++nt) {
        float bias = bl[nt * 16 + m];
#pragma unroll
        for (int r = 0; r < 4; ++r) {
            int row = row0 + g * 4 + r;
            float v = acc[nt][r] + bias;
            if constexpr (OUTBF) {
                unsigned short hb = f2bf(v);
                ohi[(size_t)row * 64 + nt * 16 + m] = hb;
                olo[(size_t)row * 64 + nt * 16 + m] = f2bf(v - bf2f(hb));
            } else {
                outf[(size_t)row * 64 + nt * 16 + m] = v;
            }
        }
    }
}

__global__ __launch_bounds__(256) void k_pool(const float* __restrict__ h,
                                              const int* __restrict__ batch,
                                              float* __restrict__ pooled) {
    int lane = threadIdx.x & 63;
    int wave = (blockIdx.x * blockDim.x + threadIdx.x) >> 6;
    int nWaves = (gridDim.x * blockDim.x) >> 6;
    int per = (N_NODES + nWaves - 1) / nWaves;
    int beg = wave * per;
    int end = beg + per; if (end > N_NODES) end = N_NODES;
    if (beg >= end) return;
    int curg = batch[beg];
    float m = -INFINITY;
    for (int i = beg; i < end; ++i) {
        int g = batch[i];
        if (g != curg) {
            atomicMaxFloat(&pooled[curg * 64 + lane], m);
            m = -INFINITY;
            curg = g;
        }
        m = fmaxf(m, h[(size_t)i * 64 + lane]);
    }
    atomicMaxFloat(&pooled[curg * 64 + lane], m);
}

__global__ void k_head(const float* __restrict__ pooled,
                       const float* __restrict__ Wout,
                       const float* __restrict__ bout, float* __restrict__ out) {
    int tid = threadIdx.x;          // 512 threads: g = tid>>3, o = tid&7
    int g = tid >> 3, o = tid & 7;
    float acc = bout[o];
#pragma unroll
    for (int k = 0; k < 64; ++k) acc += pooled[g * 64 + k] * Wout[k * 8 + o];
    float mx = acc;
#pragma unroll
    for (int m = 1; m < 8; m <<= 1) mx = fmaxf(mx, __shfl_xor(mx, m));
    float ex = expf(acc - mx);
    float sum = ex;
#pragma unroll
    for (int m = 1; m < 8; m <<= 1) sum += __shfl_xor(sum, m);
    out[g * 8 + o] = (acc - mx) - logf(sum);
}

extern "C" void kernel_launch(void* const* d_in, const int* in_sizes, int n_in,
                              void* d_out, int out_size, void* d_ws, size_t ws_size,
                              hipStream_t stream) {
    const float* x    = (const float*)d_in[0];
    const float* Wl0  = (const float*)d_in[1];
    const float* bl0  = (const float*)d_in[2];
    const float* Wr0  = (const float*)d_in[3];
    const float* Wl1  = (const float*)d_in[4];
    const float* bl1  = (const float*)d_in[5];
    const float* Wr1  = (const float*)d_in[6];
    const float* Wl2  = (const float*)d_in[7];
    const float* bl2  = (const float*)d_in[8];
    const float* Wr2  = (const float*)d_in[9];
    const float* Wout = (const float*)d_in[10];
    const float* bout = (const float*)d_in[11];
    const int*   eidx = (const int*)d_in[12];
    const int*   batch= (const int*)d_in[13];
    const int* src = eidx;
    const int* dst = eidx + N_EDGES;

    uint8_t* ws = (uint8_t*)d_ws;
    int*   S       = (int*)(ws + 0);                // 50177 ints
    int*   row_ptr = (int*)(ws + 400128);
    int*   col     = (int*)(ws + 800256);
    float* pooled  = (float*)(ws + 7200384);
    float* M       = (float*)(ws + 7217408);
    int2*  pairs   = (int2*)(ws + 7217408);         // aliases M (dead before agg)
    unsigned short* Hhi = (unsigned short*)(ws + 32817408);
    unsigned short* Hlo = (unsigned short*)(ws + 45617408);

    k_init<<<16, 256, 0, stream>>>(pooled);
    k_rhist<<<NCHUNK, 256, 0, stream>>>(dst, S);
    k_rscan<<<1, 1024, 0, stream>>>(S);
    k_rscatter<<<NCHUNK, 256, 0, stream>>>(src, dst, S, pairs);
    k_rbuild<<<NBKT, 256, 0, stream>>>(pairs, S, row_ptr, col);
    k_xcast<<<(N_NODES * 32 / 8 + 255) / 256, 256, 0, stream>>>(x, Hhi);

    int aggBlocks = (N_NODES / NC + 3) / 4;        // 1563
    int mfmaBlocks = (N_NODES / 16 + 3) / 4;       // 1563

    // layer 0: mean0 (from x-hi gathers) -> M; h1 -> Hhi/Hlo (overwrites x-hi)
    k_agg_bf<32><<<aggBlocks, 256, 0, stream>>>(Hhi, row_ptr, col, M);
    k_dense_mfma<32, false, 32, 32, true><<<mfmaBlocks, 256, 0, stream>>>(
        M, x, nullptr, nullptr, Wl0, bl0, Wr0, nullptr, Hhi, Hlo);
    // layer 1: mean1 (from h1-hi gathers) -> M; h2 -> Hhi/Hlo (in-place)
    k_agg_bf<64><<<aggBlocks, 256, 0, stream>>>(Hhi, row_ptr, col, M);
    k_dense_mfma<64, true, 64, 64, true><<<mfmaBlocks, 256, 0, stream>>>(
        M, nullptr, Hhi, Hlo, Wl1, bl1, Wr1, nullptr, Hhi, Hlo);
    // layer 2: mean2 -> M; h3 (fp32) -> M in-place; pool reads M
    k_agg_bf<64><<<aggBlocks, 256, 0, stream>>>(Hhi, row_ptr, col, M);
    k_dense_mfma<64, true, 64, 64, false><<<mfmaBlocks, 256, 0, stream>>>(
        M, nullptr, Hhi, Hlo, Wl2, bl2, Wr2, M, nullptr, nullptr);

    k_pool<<<256, 256, 0, stream>>>(M, batch, pooled);
    k_head<<<1, 512, 0, stream>>>(pooled, Wout, bout, (float*)d_out);
}